// Round 2
// 739.372 us; speedup vs baseline: 1.1828x; 1.1828x over previous
//
#include <hip/hip_runtime.h>
#include <stdint.h>

#define Bsz 4
#define Lseq 4096
#define Dm 1024
#define Hh 16
#define Wc 256
#define FFd 4096
#define NC 16
#define NTOK (Bsz * Lseq)   // 16384

typedef unsigned short u16;

__device__ __forceinline__ float bf2f(u16 u) {
  union { unsigned int i; float f; } v; v.i = ((unsigned int)u) << 16; return v.f;
}
__device__ __forceinline__ u16 f2bf(float f) {
  union { float f; unsigned int i; } v; v.f = f;
  unsigned int r = v.i + 0x7fffu + ((v.i >> 16) & 1u);
  return (u16)(r >> 16);
}
__device__ __forceinline__ unsigned int pack2bf(float a, float b) {
  union { float f; unsigned int u; } x, y; x.f = a; y.f = b;
  return ((x.u + 0x8000u) >> 16) | ((y.u + 0x8000u) & 0xffff0000u);
}

// ---------------- utility kernels ----------------
__global__ void cvt_f32_bf16(const float* __restrict__ in, u16* __restrict__ out, long n) {
  long i = ((long)blockIdx.x * blockDim.x + threadIdx.x) * 4;
  if (i >= n) return;
  float4 v = *(const float4*)(in + i);
  u16 o[4] = { f2bf(v.x), f2bf(v.y), f2bf(v.z), f2bf(v.w) };
  *(uint2*)(out + i) = *(const uint2*)o;
}

__global__ void transpose_f32_bf16(const float* __restrict__ in, u16* __restrict__ out,
                                   int R, int C) {
  __shared__ float tile[32][33];
  int tx = threadIdx.x & 31, ty = threadIdx.x >> 5;       // 32 x 8
  int r0 = blockIdx.y * 32, c0 = blockIdx.x * 32;
#pragma unroll
  for (int k = 0; k < 4; ++k)
    tile[ty + 8 * k][tx] = in[(size_t)(r0 + ty + 8 * k) * C + c0 + tx];
  __syncthreads();
#pragma unroll
  for (int k = 0; k < 4; ++k)
    out[(size_t)(c0 + ty + 8 * k) * R + r0 + tx] = f2bf(tile[tx][ty + 8 * k]);
}

// ---------------- GEMM: 256x256 tile, BK=64, 8-phase counted-vmcnt schedule ----
typedef __attribute__((ext_vector_type(8))) short s16x8;
typedef __attribute__((ext_vector_type(4))) float fx4;
typedef __attribute__((address_space(1))) unsigned int as1u;
typedef __attribute__((address_space(3))) unsigned int as3u;

__device__ __forceinline__ void gll16(const void* g, void* l) {
  __builtin_amdgcn_global_load_lds((as1u*)g, (as3u*)l, 16, 0, 0);
}

// XCD-partition swizzle: xcd = flat % 8. Row-blocks partitioned by mb%8==xcd,
// column-outer within an XCD so consecutive same-XCD blocks share a B-strip.
__device__ __forceinline__ void swizzle_mn(int MB, int NB, int* mb, int* nb) {
  int flat = blockIdx.y * NB + blockIdx.x;
  if ((MB & 7) == 0) {
    int xcd = flat & 7;
    int j = flat >> 3;
    int rpx = MB >> 3;
    *nb = j / rpx;
    int rowin = j - *nb * rpx;
    *mb = (rowin << 3) | xcd;
  } else {
    *mb = blockIdx.y; *nb = blockIdx.x;
  }
}

// Stage one 16KB half-tile segment: 16 wave-loads of 8 rows x 64 cols (1KB each).
// LDS dest is LINEAR [256][64] bf16; bank-swizzle is applied by permuting the
// GLOBAL source chunk (rule #21): phys chunk c holds logical chunk c ^ (row&7).
// rs == 0 (mod 8) so row&7 == lane>>3 within each 8-row granule.
__device__ __forceinline__ void stage_seg(const u16* __restrict__ G, int ld, int k0,
                                          u16* L, int rb0, int rb1,
                                          int wid, int lane) {
#pragma unroll
  for (int i = 0; i < 2; ++i) {
    int j = wid * 2 + i;
    int rs = (j < 8) ? (rb0 + j * 8) : (rb1 + (j - 8) * 8);   // wave-uniform
    int grow = rs + (lane >> 3);
    int gcol = k0 + (((lane & 7) ^ (lane >> 3)) << 3);
    gll16(G + (size_t)grow * ld + gcol, L + rs * 64);
  }
}

#define MFMA_Q(MQ, NQ)                                                           \
  {                                                                              \
    _Pragma("unroll") for (int mt = 0; mt < 4; ++mt) {                           \
      _Pragma("unroll") for (int nt = 0; nt < 2; ++nt) {                         \
        acc[(MQ)*4 + mt][(NQ)*2 + nt] = __builtin_amdgcn_mfma_f32_16x16x32_bf16( \
            af[mt][0], bfr[NQ][nt][0], acc[(MQ)*4 + mt][(NQ)*2 + nt], 0, 0, 0);  \
        acc[(MQ)*4 + mt][(NQ)*2 + nt] = __builtin_amdgcn_mfma_f32_16x16x32_bf16( \
            af[mt][1], bfr[NQ][nt][1], acc[(MQ)*4 + mt][(NQ)*2 + nt], 0, 0, 0);  \
      }                                                                          \
    }                                                                            \
  }

// C[M,N] = A[M,K](bf16, row stride lda) * B[N,K](bf16)^T (+bias). 512 threads,
// 8 waves in 2(M) x 4(N); per-wave output 128x64. 128 KiB LDS, 2 K-tile dbuf.
// Phase order (mq,nq): (0,0)(0,1)(1,1)(1,0). A-mq0 LDS region dies after ph1,
// A-mq1 after ph3 -> A(t+2) stages into the CURRENT buffer at ph3/ph4 behind
// the reads; B(t+1) stages into the other buffer at ph1/ph2. Boundary wait is
// vmcnt(4): tile t+1 fully landed, A(t+2) (4 loads) still in flight.
template <int RELU, int OUTBF16, int HASBIAS>
__global__ __launch_bounds__(512, 2) void gemm256(const u16* A, int lda,
                                                  const u16* Bm,
                                                  const float* __restrict__ bias,
                                                  void* Cp,
                                                  int M, int N, int K) {
  __shared__ __attribute__((aligned(16))) u16 As[2][256 * 64];
  __shared__ __attribute__((aligned(16))) u16 Bs[2][256 * 64];
  int tid = threadIdx.x;
  int lane = tid & 63, wid = tid >> 6;
  int lm = lane & 15, quad = lane >> 4;
  int wr = wid >> 2, wc = wid & 3;
  int mb, nb;
  swizzle_mn(gridDim.y, gridDim.x, &mb, &nb);
  int m0 = mb * 256, n0 = nb * 256;
  const u16* Ag = A + (size_t)m0 * lda;
  const u16* Bg = Bm + (size_t)n0 * K;
  int NT = K >> 6;

  // swizzled read offsets (elements): logical chunk (ks*4+quad) ^ (row&7), row&7==lm&7
  int off0 = (quad ^ (lm & 7)) << 3;
  int off1 = ((4 + quad) ^ (lm & 7)) << 3;

  fx4 acc[8][4] = {};

  // prologue: tile0 A+B, tile1 A. vmcnt(4) -> tile0 landed, tile1-A in flight.
  stage_seg(Ag, lda, 0, As[0], 0, 128, wid, lane);
  stage_seg(Ag, lda, 0, As[0], 64, 192, wid, lane);
  stage_seg(Bg, K, 0, Bs[0], 0, 64, wid, lane);
  stage_seg(Bg, K, 0, Bs[0], 128, 192, wid, lane);
  if (NT > 1) {
    stage_seg(Ag, lda, 64, As[1], 0, 128, wid, lane);
    stage_seg(Ag, lda, 64, As[1], 64, 192, wid, lane);
    asm volatile("s_waitcnt vmcnt(4)" ::: "memory");
  } else {
    asm volatile("s_waitcnt vmcnt(0)" ::: "memory");
  }
  __builtin_amdgcn_s_barrier();

  s16x8 af[4][2];
  s16x8 bfr[2][2][2];

  for (int t = 0; t < NT; ++t) {
    const u16* Ac = As[t & 1];
    const u16* Bc = Bs[t & 1];
    u16* Bn = Bs[(t + 1) & 1];
    u16* An2 = As[t & 1];        // t+2 has same parity
    int kn = (t + 1) << 6, kn2 = (t + 2) << 6;

    // ---- phase 1: quadrant (mq0, nq0); stage B(t+1) seg0
#pragma unroll
    for (int mt = 0; mt < 4; ++mt) {
      int r = wr * 128 + mt * 16 + lm;
      af[mt][0] = *(const s16x8*)(Ac + r * 64 + off0);
      af[mt][1] = *(const s16x8*)(Ac + r * 64 + off1);
    }
#pragma unroll
    for (int nt = 0; nt < 2; ++nt) {
      int r = wc * 64 + nt * 16 + lm;
      bfr[0][nt][0] = *(const s16x8*)(Bc + r * 64 + off0);
      bfr[0][nt][1] = *(const s16x8*)(Bc + r * 64 + off1);
    }
    if (t + 1 < NT) stage_seg(Bg, K, kn, Bn, 0, 64, wid, lane);
    __builtin_amdgcn_s_barrier();
    asm volatile("s_waitcnt lgkmcnt(0)" ::: "memory");
    __builtin_amdgcn_s_setprio(1);
    MFMA_Q(0, 0)
    __builtin_amdgcn_s_setprio(0);
    __builtin_amdgcn_s_barrier();

    // ---- phase 2: (mq0, nq1); stage B(t+1) seg1
#pragma unroll
    for (int nt = 0; nt < 2; ++nt) {
      int r = wc * 64 + 32 + nt * 16 + lm;
      bfr[1][nt][0] = *(const s16x8*)(Bc + r * 64 + off0);
      bfr[1][nt][1] = *(const s16x8*)(Bc + r * 64 + off1);
    }
    if (t + 1 < NT) stage_seg(Bg, K, kn, Bn, 128, 192, wid, lane);
    __builtin_amdgcn_s_barrier();
    asm volatile("s_waitcnt lgkmcnt(0)" ::: "memory");
    __builtin_amdgcn_s_setprio(1);
    MFMA_Q(0, 1)
    __builtin_amdgcn_s_setprio(0);
    __builtin_amdgcn_s_barrier();

    // ---- phase 3: (mq1, nq1); stage A(t+2) seg0 (rows {0-63,128-191}: dead since ph1)
#pragma unroll
    for (int mt = 0; mt < 4; ++mt) {
      int r = wr * 128 + 64 + mt * 16 + lm;
      af[mt][0] = *(const s16x8*)(Ac + r * 64 + off0);
      af[mt][1] = *(const s16x8*)(Ac + r * 64 + off1);
    }
    if (t + 2 < NT) stage_seg(Ag, lda, kn2, An2, 0, 128, wid, lane);
    __builtin_amdgcn_s_barrier();
    asm volatile("s_waitcnt lgkmcnt(0)" ::: "memory");
    __builtin_amdgcn_s_setprio(1);
    MFMA_Q(1, 1)
    __builtin_amdgcn_s_setprio(0);
    __builtin_amdgcn_s_barrier();

    // ---- phase 4: (mq1, nq0); stage A(t+2) seg1; K-tile boundary wait
    if (t + 2 < NT) {
      stage_seg(Ag, lda, kn2, An2, 64, 192, wid, lane);
      asm volatile("s_waitcnt vmcnt(4)" ::: "memory");
    } else if (t + 2 == NT) {
      asm volatile("s_waitcnt vmcnt(0)" ::: "memory");
    }
    __builtin_amdgcn_s_barrier();
    __builtin_amdgcn_s_setprio(1);
    MFMA_Q(1, 0)
    __builtin_amdgcn_s_setprio(0);
    __builtin_amdgcn_s_barrier();
  }

  // epilogue
  float* Cf = (float*)Cp;
  u16* Ch = (u16*)Cp;
#pragma unroll
  for (int ai = 0; ai < 8; ++ai) {
#pragma unroll
    for (int bi = 0; bi < 4; ++bi) {
      int col = n0 + wc * 64 + (bi >> 1) * 32 + (bi & 1) * 16 + lm;
      float bv = HASBIAS ? bias[col] : 0.f;
#pragma unroll
      for (int r = 0; r < 4; ++r) {
        int row = m0 + wr * 128 + (ai >> 2) * 64 + (ai & 3) * 16 + quad * 4 + r;
        float v = acc[ai][bi][r] + bv;
        if (RELU) v = v > 0.f ? v : 0.f;
        if (OUTBF16) Ch[(size_t)row * N + col] = f2bf(v);
        else         Cf[(size_t)row * N + col] = v;
      }
    }
  }
}

// ---------------- MFMA flash attention ----------------
#define PADK 72
#define PADV 136
#define PADP 40
#define PADO 72

__global__ __launch_bounds__(256, 2) void attn_mfma(u16* qkv) {
  __shared__ __attribute__((aligned(16))) u16 lds[38400];   // 76.8 KB
  u16* Klds  = lds;                    // 128 x PADK = 9216
  u16* Vtlds = lds + 9216;             // 64 x PADV  = 8704

  int bid = blockIdx.x;
  int h = bid & (Hh - 1);
  int c = (bid >> 4) & (NC - 1);
  int b = bid >> 8;
  int tid = threadIdx.x, lane = tid & 63, w = tid >> 6;
  int lm = lane & 15, quad = lane >> 4;
  u16* Pw = lds + 17920 + w * 5120;

  size_t rowbase = (size_t)b * Lseq;

  s16x8 qf[4][2];
#pragma unroll
  for (int nt = 0; nt < 4; ++nt)
#pragma unroll
    for (int ks = 0; ks < 2; ++ks) {
      int qtok = c * Wc + w * 64 + nt * 16 + lm;
      qf[nt][ks] = *(const s16x8*)(qkv + (rowbase + qtok) * 3072 + h * 64 + ks * 32 + quad * 8);
    }

  fx4 acc_o[4][4] = {};
  float lsum[4] = {0.f, 0.f, 0.f, 0.f};

  int nph = (c > 0) ? 4 : 2;
  int t0  = (c > 0) ? (c - 1) * Wc : 0;

  for (int ph = 0; ph < nph; ++ph) {
    int kt0 = t0 + ph * 128;
    __syncthreads();

#pragma unroll
    for (int it = 0; it < 4; ++it) {
      int s = tid + it * 256;
      int row = s >> 3, off = (s & 7) * 8;
      uint4 kv = *(const uint4*)(qkv + (rowbase + kt0 + row) * 3072 + 1024 + h * 64 + off);
      *(uint4*)(Klds + row * PADK + off) = kv;
    }
    {
      int d = lane;
      int kb = w * 32;
      u16 tmp[32];
#pragma unroll
      for (int i = 0; i < 32; ++i)
        tmp[i] = qkv[(rowbase + kt0 + kb + i) * 3072 + 2048 + h * 64 + d];
#pragma unroll
      for (int i = 0; i < 4; ++i)
        *(uint4*)(Vtlds + d * PADV + kb + i * 8) = *(const uint4*)(tmp + i * 8);
    }
    __syncthreads();

#pragma unroll
    for (int kt = 0; kt < 4; ++kt) {
      u16* Pb = Pw + (kt & 1) * 2560;
      fx4 sa[2][4] = {};
#pragma unroll
      for (int ks = 0; ks < 2; ++ks) {
        s16x8 kf0 = *(const s16x8*)(Klds + (kt * 32 + lm) * PADK + ks * 32 + quad * 8);
        s16x8 kf1 = *(const s16x8*)(Klds + (kt * 32 + 16 + lm) * PADK + ks * 32 + quad * 8);
#pragma unroll
        for (int nt = 0; nt < 4; ++nt) {
          sa[0][nt] = __builtin_amdgcn_mfma_f32_16x16x32_bf16(kf0, qf[nt][ks], sa[0][nt], 0, 0, 0);
          sa[1][nt] = __builtin_amdgcn_mfma_f32_16x16x32_bf16(kf1, qf[nt][ks], sa[1][nt], 0, 0, 0);
        }
      }
#pragma unroll
      for (int mt = 0; mt < 2; ++mt)
#pragma unroll
        for (int nt = 0; nt < 4; ++nt) {
          float e0 = __expf(sa[mt][nt][0] * 0.125f);
          float e1 = __expf(sa[mt][nt][1] * 0.125f);
          float e2 = __expf(sa[mt][nt][2] * 0.125f);
          float e3 = __expf(sa[mt][nt][3] * 0.125f);
          lsum[nt] += (e0 + e1) + (e2 + e3);
          uint2 pk; pk.x = pack2bf(e0, e1); pk.y = pack2bf(e2, e3);
          *(uint2*)(Pb + (nt * 16 + lm) * PADP + mt * 16 + quad * 4) = pk;
        }
#pragma unroll
      for (int mt = 0; mt < 4; ++mt) {
        s16x8 vf = *(const s16x8*)(Vtlds + (mt * 16 + lm) * PADV + kt * 32 + quad * 8);
#pragma unroll
        for (int nt = 0; nt < 4; ++nt) {
          s16x8 pf = *(const s16x8*)(Pb + (nt * 16 + lm) * PADP + quad * 8);
          acc_o[mt][nt] = __builtin_amdgcn_mfma_f32_16x16x32_bf16(vf, pf, acc_o[mt][nt], 0, 0, 0);
        }
      }
    }
  }

#pragma unroll
  for (int nt = 0; nt < 4; ++nt) {
    float v = lsum[nt];
    v += __shfl_xor(v, 16, 64);
    v += __shfl_xor(v, 32, 64);
    lsum[nt] = 1.f / v;
  }

  __syncthreads();
  u16* Obuf = lds;
#pragma unroll
  for (int mt = 0; mt < 4; ++mt)
#pragma unroll
    for (int nt = 0; nt < 4; ++nt) {
      float inv = lsum[nt];
      uint2 pk;
      pk.x = pack2bf(acc_o[mt][nt][0] * inv, acc_o[mt][nt][1] * inv);
      pk.y = pack2bf(acc_o[mt][nt][2] * inv, acc_o[mt][nt][3] * inv);
      int q = nt * 16 + lm;
      *(uint2*)(Obuf + (w * 64 + q) * PADO + mt * 16 + quad * 4) = pk;
    }
  __syncthreads();
#pragma unroll
  for (int it = 0; it < 8; ++it) {
    int s = tid + it * 256;
    int row = s >> 3, chunk = s & 7;
    uint4 v = *(const uint4*)(Obuf + row * PADO + chunk * 8);
    *(uint4*)(qkv + (rowbase + c * Wc + row) * 3072 + h * 64 + chunk * 8) = v;
  }
}

// ---------------- layernorm variants ----------------
__device__ __forceinline__ void ln_core(float sx, float sy, float sz, float sw,
                                        const float* gamma, const float* beta, int tid,
                                        float* red, float4* outv) {
  float part = sx + sy + sz + sw;
#pragma unroll
  for (int off = 32; off > 0; off >>= 1) part += __shfl_down(part, off, 64);
  if ((tid & 63) == 0) red[tid >> 6] = part;
  __syncthreads();
  float mean = (red[0] + red[1] + red[2] + red[3]) * (1.f / 1024.f);
  __syncthreads();

  float dx = sx - mean, dy = sy - mean, dz = sz - mean, dw = sw - mean;
  float sq = dx * dx + dy * dy + dz * dz + dw * dw;
#pragma unroll
  for (int off = 32; off > 0; off >>= 1) sq += __shfl_down(sq, off, 64);
  if ((tid & 63) == 0) red[tid >> 6] = sq;
  __syncthreads();
  float var = (red[0] + red[1] + red[2] + red[3]) * (1.f / 1024.f);
  float rs = rsqrtf(var + 1e-6f);

  float4 g = *(const float4*)(gamma + tid * 4);
  float4 be = *(const float4*)(beta + tid * 4);
  outv->x = g.x * dx * rs + be.x;
  outv->y = g.y * dy * rs + be.y;
  outv->z = g.z * dz * rs + be.z;
  outv->w = g.w * dw * rs + be.w;
}

__global__ __launch_bounds__(256) void ln1_kernel(const float* __restrict__ r,
                                                  const float* __restrict__ dl,
                                                  const float* __restrict__ gamma,
                                                  const float* __restrict__ beta,
                                                  u16* __restrict__ outh) {
  __shared__ float red[4];
  int row = blockIdx.x, tid = threadIdx.x;
  size_t base = (size_t)row * Dm;
  float4 rv = *(const float4*)(r + base + tid * 4);
  float4 dv = *(const float4*)(dl + base + tid * 4);
  float4 o;
  ln_core(rv.x + dv.x, rv.y + dv.y, rv.z + dv.z, rv.w + dv.w, gamma, beta, tid, red, &o);
  u16 u[4] = { f2bf(o.x), f2bf(o.y), f2bf(o.z), f2bf(o.w) };
  *(uint2*)(outh + base + tid * 4) = *(const uint2*)u;
}

// LN2: sum = bf16 x1 + f32 y2 + colbias (bf2); -> f32 out (in-place ok)
__global__ __launch_bounds__(256) void ln2_kernel(const u16* __restrict__ r,
                                                  const float* dl,
                                                  const float* __restrict__ colbias,
                                                  const float* __restrict__ gamma,
                                                  const float* __restrict__ beta,
                                                  float* outf) {
  __shared__ float red[4];
  int row = blockIdx.x, tid = threadIdx.x;
  size_t base = (size_t)row * Dm;
  uint2 ru = *(const uint2*)(r + base + tid * 4);
  const u16* pu = (const u16*)&ru;
  float4 dv = *(const float4*)(dl + base + tid * 4);
  float4 bb = *(const float4*)(colbias + tid * 4);
  float4 o;
  ln_core(bf2f(pu[0]) + dv.x + bb.x, bf2f(pu[1]) + dv.y + bb.y,
          bf2f(pu[2]) + dv.z + bb.z, bf2f(pu[3]) + dv.w + bb.w,
          gamma, beta, tid, red, &o);
  *(float4*)(outf + base + tid * 4) = o;
}

// ---------------- launch ----------------
extern "C" void kernel_launch(void* const* d_in, const int* in_sizes, int n_in,
                              void* d_out, int out_size, void* d_ws, size_t ws_size,
                              hipStream_t stream) {
  const float* x         = (const float*)d_in[0];
  const float* in_proj_w = (const float*)d_in[1];
  const float* in_proj_b = (const float*)d_in[2];
  const float* out_w     = (const float*)d_in[3];
  const float* out_b     = (const float*)d_in[4];
  const float* gamma1    = (const float*)d_in[5];
  const float* beta1     = (const float*)d_in[6];
  const float* w1        = (const float*)d_in[7];
  const float* bf1       = (const float*)d_in[8];
  const float* w2        = (const float*)d_in[9];
  const float* bf2       = (const float*)d_in[10];
  const float* gamma2    = (const float*)d_in[11];
  const float* beta2     = (const float*)d_in[12];
  float* out = (float*)d_out;

  char* ws = (char*)d_ws;
  size_t off = 0;
  auto alloc = [&](size_t bytes) -> char* {
    char* p = ws + off;
    off += (bytes + 255) & ~(size_t)255;
    return p;
  };
  u16* wqkvh = (u16*)alloc((size_t)3 * Dm * Dm * 2);
  u16* owh   = (u16*)alloc((size_t)Dm * Dm * 2);
  u16* w1th  = (u16*)alloc((size_t)FFd * Dm * 2);
  u16* w2th  = (u16*)alloc((size_t)Dm * FFd * 2);
  u16* big   = (u16*)alloc((size_t)NTOK * FFd * 2);
  u16* x1h   = (u16*)alloc((size_t)NTOK * Dm * 2);
  u16* qkvh = big;
  u16* hh   = big;
  u16* xh   = (u16*)d_out;
  float* attnf = out;
  float* y2f   = out;

  cvt_f32_bf16<<<(long)NTOK * Dm / 1024, 256, 0, stream>>>(x, xh, (long)NTOK * Dm);
  cvt_f32_bf16<<<(long)3 * Dm * Dm / 1024, 256, 0, stream>>>(in_proj_w, wqkvh, (long)3 * Dm * Dm);
  cvt_f32_bf16<<<(long)Dm * Dm / 1024, 256, 0, stream>>>(out_w, owh, (long)Dm * Dm);
  transpose_f32_bf16<<<dim3(FFd / 32, Dm / 32), 256, 0, stream>>>(w1, w1th, Dm, FFd);
  transpose_f32_bf16<<<dim3(Dm / 32, FFd / 32), 256, 0, stream>>>(w2, w2th, FFd, Dm);

  // QKV projection: [16384,1024] x [3072,1024]^T -> bf16 [16384,3072]
  gemm256<0, 1, 1><<<dim3(3 * Dm / 256, NTOK / 256), 512, 0, stream>>>(
      xh, Dm, wqkvh, in_proj_b, qkvh, NTOK, 3 * Dm, Dm);

  attn_mfma<<<Bsz * NC * Hh, 256, 0, stream>>>(qkvh);

  // out projection: attn-out (qkv cols 0..1023) x out_w^T -> f32
  gemm256<0, 0, 1><<<dim3(Dm / 256, NTOK / 256), 512, 0, stream>>>(
      qkvh, 3 * Dm, owh, out_b, attnf, NTOK, Dm, Dm);

  ln1_kernel<<<NTOK, 256, 0, stream>>>(x, attnf, gamma1, beta1, x1h);

  // FFN1 + ReLU -> bf16 [16384,4096]
  gemm256<1, 1, 1><<<dim3(FFd / 256, NTOK / 256), 512, 0, stream>>>(
      x1h, Dm, w1th, bf1, hh, NTOK, FFd, Dm);

  // FFN2 -> f32 (bias bf2 folded into LN2); no split-K, no atomics
  gemm256<0, 0, 0><<<dim3(Dm / 256, NTOK / 256), 512, 0, stream>>>(
      hh, FFd, w2th, (const float*)nullptr, y2f, NTOK, Dm, FFd);

  ln2_kernel<<<NTOK, 256, 0, stream>>>(x1h, y2f, bf2, gamma2, beta2, out);
}

// Round 3
// 691.663 us; speedup vs baseline: 1.2644x; 1.0690x over previous
//
#include <hip/hip_runtime.h>
#include <stdint.h>

#define Bsz 4
#define Lseq 4096
#define Dm 1024
#define Hh 16
#define Wc 256
#define FFd 4096
#define NC 16
#define NTOK (Bsz * Lseq)   // 16384

typedef unsigned short u16;

__device__ __forceinline__ float bf2f(u16 u) {
  union { unsigned int i; float f; } v; v.i = ((unsigned int)u) << 16; return v.f;
}
__device__ __forceinline__ u16 f2bf(float f) {
  union { float f; unsigned int i; } v; v.f = f;
  unsigned int r = v.i + 0x7fffu + ((v.i >> 16) & 1u);
  return (u16)(r >> 16);
}
__device__ __forceinline__ unsigned int pack2bf(float a, float b) {
  union { float f; unsigned int u; } x, y; x.f = a; y.f = b;
  return ((x.u + 0x8000u) >> 16) | ((y.u + 0x8000u) & 0xffff0000u);
}

// ---------------- utility kernels ----------------
__global__ void cvt_f32_bf16(const float* __restrict__ in, u16* __restrict__ out, long n) {
  long i = ((long)blockIdx.x * blockDim.x + threadIdx.x) * 4;
  if (i >= n) return;
  float4 v = *(const float4*)(in + i);
  u16 o[4] = { f2bf(v.x), f2bf(v.y), f2bf(v.z), f2bf(v.w) };
  *(uint2*)(out + i) = *(const uint2*)o;
}

__global__ void transpose_f32_bf16(const float* __restrict__ in, u16* __restrict__ out,
                                   int R, int C) {
  __shared__ float tile[32][33];
  int tx = threadIdx.x & 31, ty = threadIdx.x >> 5;       // 32 x 8
  int r0 = blockIdx.y * 32, c0 = blockIdx.x * 32;
#pragma unroll
  for (int k = 0; k < 4; ++k)
    tile[ty + 8 * k][tx] = in[(size_t)(r0 + ty + 8 * k) * C + c0 + tx];
  __syncthreads();
#pragma unroll
  for (int k = 0; k < 4; ++k)
    out[(size_t)(c0 + ty + 8 * k) * R + r0 + tx] = f2bf(tile[tx][ty + 8 * k]);
}

// ---------------- GEMM: 256x256 tile, BK=64, 8-phase counted-vmcnt schedule ----
typedef __attribute__((ext_vector_type(8))) short s16x8;
typedef __attribute__((ext_vector_type(4))) float fx4;
typedef __attribute__((address_space(1))) unsigned int as1u;
typedef __attribute__((address_space(3))) unsigned int as3u;
typedef __attribute__((address_space(3))) const u16 l16c;

__device__ __forceinline__ void gll16(const void* g, void* l) {
  __builtin_amdgcn_global_load_lds((as1u*)g, (as3u*)l, 16, 0, 0);
}

// Inline-asm LDS fragment read: invisible to the compiler's alias/waitcnt
// machinery so it cannot insert drains against in-flight global_load_lds.
// Consumers MUST be preceded by s_waitcnt lgkmcnt(0) + sched_barrier(0).
__device__ __forceinline__ s16x8 ldsread(const u16* p) {
  s16x8 r;
  unsigned a = (unsigned)(size_t)(l16c*)p;
  asm volatile("ds_read_b128 %0, %1" : "=v"(r) : "v"(a));
  return r;
}

// XCD-partition swizzle: xcd = flat % 8. Row-blocks partitioned by mb%8==xcd,
// column-outer within an XCD so consecutive same-XCD blocks share a B-strip.
__device__ __forceinline__ void swizzle_mn(int MB, int NB, int* mb, int* nb) {
  int flat = blockIdx.y * NB + blockIdx.x;
  if ((MB & 7) == 0) {
    int xcd = flat & 7;
    int j = flat >> 3;
    int rpx = MB >> 3;
    *nb = j / rpx;
    int rowin = j - *nb * rpx;
    *mb = (rowin << 3) | xcd;
  } else {
    *mb = blockIdx.y; *nb = blockIdx.x;
  }
}

// Stage one 16KB half-tile segment: 16 wave-loads of 8 rows x 64 cols (1KB each).
// LDS dest is LINEAR [256][64] bf16; bank-swizzle is applied by permuting the
// GLOBAL source chunk (rule #21): phys chunk c holds logical chunk c ^ (row&7).
__device__ __forceinline__ void stage_seg(const u16* __restrict__ G, int ld, int k0,
                                          u16* L, int rb0, int rb1,
                                          int wid, int lane) {
#pragma unroll
  for (int i = 0; i < 2; ++i) {
    int j = wid * 2 + i;
    int rs = (j < 8) ? (rb0 + j * 8) : (rb1 + (j - 8) * 8);   // wave-uniform
    int grow = rs + (lane >> 3);
    int gcol = k0 + (((lane & 7) ^ (lane >> 3)) << 3);
    gll16(G + (size_t)grow * ld + gcol, L + rs * 64);
  }
}

#define MFMA_Q(MQ, NQ)                                                           \
  {                                                                              \
    _Pragma("unroll") for (int mt = 0; mt < 4; ++mt) {                           \
      _Pragma("unroll") for (int nt = 0; nt < 2; ++nt) {                         \
        acc[(MQ)*4 + mt][(NQ)*2 + nt] = __builtin_amdgcn_mfma_f32_16x16x32_bf16( \
            af[mt][0], bfr[NQ][nt][0], acc[(MQ)*4 + mt][(NQ)*2 + nt], 0, 0, 0);  \
        acc[(MQ)*4 + mt][(NQ)*2 + nt] = __builtin_amdgcn_mfma_f32_16x16x32_bf16( \
            af[mt][1], bfr[NQ][nt][1], acc[(MQ)*4 + mt][(NQ)*2 + nt], 0, 0, 0);  \
      }                                                                          \
    }                                                                            \
  }

#define WAIT_LGKM_FENCE()                                  \
  asm volatile("s_waitcnt lgkmcnt(0)" ::: "memory");       \
  __builtin_amdgcn_sched_barrier(0);

// C[M,N] = A[M,K](bf16, row stride lda) * B[N,K](bf16)^T (+bias). 512 threads,
// 8 waves in 2(M) x 4(N); per-wave output 128x64. 128 KiB LDS, 2 K-tile dbuf.
// Phase order (mq,nq): (0,0)(0,1)(1,1)(1,0). A-mq0 LDS region dies after ph1,
// A-mq1 after ph3 -> A(t+2) stages into the CURRENT buffer at ph3/ph4 behind
// the reads; B(t+1) stages into the other buffer at ph1/ph2. Boundary wait is
// vmcnt(4): tile t+1 fully landed, A(t+2) (4 loads) still in flight.
template <int RELU, int OUTBF16, int HASBIAS>
__global__ __launch_bounds__(512, 2) void gemm256(const u16* A, int lda,
                                                  const u16* Bm,
                                                  const float* __restrict__ bias,
                                                  void* Cp,
                                                  int M, int N, int K) {
  __shared__ __attribute__((aligned(16))) u16 As[2][256 * 64];
  __shared__ __attribute__((aligned(16))) u16 Bs[2][256 * 64];
  int tid = threadIdx.x;
  int lane = tid & 63, wid = tid >> 6;
  int lm = lane & 15, quad = lane >> 4;
  int wr = wid >> 2, wc = wid & 3;
  int mb, nb;
  swizzle_mn(gridDim.y, gridDim.x, &mb, &nb);
  int m0 = mb * 256, n0 = nb * 256;
  const u16* Ag = A + (size_t)m0 * lda;
  const u16* Bg = Bm + (size_t)n0 * K;
  int NT = K >> 6;

  // swizzled read offsets (elements): logical chunk (ks*4+quad) ^ (row&7), row&7==lm&7
  int off0 = (quad ^ (lm & 7)) << 3;
  int off1 = ((4 + quad) ^ (lm & 7)) << 3;

  fx4 acc[8][4] = {};

  // prologue: tile0 A+B, tile1 A. vmcnt(4) -> tile0 landed, tile1-A in flight.
  stage_seg(Ag, lda, 0, As[0], 0, 128, wid, lane);
  stage_seg(Ag, lda, 0, As[0], 64, 192, wid, lane);
  stage_seg(Bg, K, 0, Bs[0], 0, 64, wid, lane);
  stage_seg(Bg, K, 0, Bs[0], 128, 192, wid, lane);
  if (NT > 1) {
    stage_seg(Ag, lda, 64, As[1], 0, 128, wid, lane);
    stage_seg(Ag, lda, 64, As[1], 64, 192, wid, lane);
    asm volatile("s_waitcnt vmcnt(4)" ::: "memory");
  } else {
    asm volatile("s_waitcnt vmcnt(0)" ::: "memory");
  }
  __builtin_amdgcn_s_barrier();

  s16x8 af[4][2];
  s16x8 bfr[2][2][2];

  for (int t = 0; t < NT; ++t) {
    const u16* Ac = As[t & 1];
    const u16* Bc = Bs[t & 1];
    u16* Bn = Bs[(t + 1) & 1];
    u16* An2 = As[t & 1];        // t+2 has same parity
    int kn = (t + 1) << 6, kn2 = (t + 2) << 6;

    // ---- phase 1: quadrant (mq0, nq0); stage B(t+1) seg0
#pragma unroll
    for (int mt = 0; mt < 4; ++mt) {
      int r = wr * 128 + mt * 16 + lm;
      af[mt][0] = ldsread(Ac + r * 64 + off0);
      af[mt][1] = ldsread(Ac + r * 64 + off1);
    }
#pragma unroll
    for (int nt = 0; nt < 2; ++nt) {
      int r = wc * 64 + nt * 16 + lm;
      bfr[0][nt][0] = ldsread(Bc + r * 64 + off0);
      bfr[0][nt][1] = ldsread(Bc + r * 64 + off1);
    }
    if (t + 1 < NT) stage_seg(Bg, K, kn, Bn, 0, 64, wid, lane);
    __builtin_amdgcn_s_barrier();
    WAIT_LGKM_FENCE()
    __builtin_amdgcn_s_setprio(1);
    MFMA_Q(0, 0)
    __builtin_amdgcn_s_setprio(0);
    __builtin_amdgcn_s_barrier();

    // ---- phase 2: (mq0, nq1); stage B(t+1) seg1
#pragma unroll
    for (int nt = 0; nt < 2; ++nt) {
      int r = wc * 64 + 32 + nt * 16 + lm;
      bfr[1][nt][0] = ldsread(Bc + r * 64 + off0);
      bfr[1][nt][1] = ldsread(Bc + r * 64 + off1);
    }
    if (t + 1 < NT) stage_seg(Bg, K, kn, Bn, 128, 192, wid, lane);
    __builtin_amdgcn_s_barrier();
    WAIT_LGKM_FENCE()
    __builtin_amdgcn_s_setprio(1);
    MFMA_Q(0, 1)
    __builtin_amdgcn_s_setprio(0);
    __builtin_amdgcn_s_barrier();

    // ---- phase 3: (mq1, nq1); stage A(t+2) seg0 (rows {0-63,128-191}: dead since ph1)
#pragma unroll
    for (int mt = 0; mt < 4; ++mt) {
      int r = wr * 128 + 64 + mt * 16 + lm;
      af[mt][0] = ldsread(Ac + r * 64 + off0);
      af[mt][1] = ldsread(Ac + r * 64 + off1);
    }
    if (t + 2 < NT) stage_seg(Ag, lda, kn2, An2, 0, 128, wid, lane);
    __builtin_amdgcn_s_barrier();
    WAIT_LGKM_FENCE()
    __builtin_amdgcn_s_setprio(1);
    MFMA_Q(1, 1)
    __builtin_amdgcn_s_setprio(0);
    __builtin_amdgcn_s_barrier();

    // ---- phase 4: (mq1, nq0); stage A(t+2) seg1; K-tile boundary wait
    if (t + 2 < NT) {
      stage_seg(Ag, lda, kn2, An2, 64, 192, wid, lane);
      asm volatile("s_waitcnt vmcnt(4)" ::: "memory");
    } else if (t + 2 == NT) {
      asm volatile("s_waitcnt vmcnt(0)" ::: "memory");
    }
    __builtin_amdgcn_s_barrier();
    __builtin_amdgcn_s_setprio(1);
    MFMA_Q(1, 0)
    __builtin_amdgcn_s_setprio(0);
    __builtin_amdgcn_s_barrier();
  }

  // epilogue
  float* Cf = (float*)Cp;
  u16* Ch = (u16*)Cp;
#pragma unroll
  for (int ai = 0; ai < 8; ++ai) {
#pragma unroll
    for (int bi = 0; bi < 4; ++bi) {
      int col = n0 + wc * 64 + (bi >> 1) * 32 + (bi & 1) * 16 + lm;
      float bv = HASBIAS ? bias[col] : 0.f;
#pragma unroll
      for (int r = 0; r < 4; ++r) {
        int row = m0 + wr * 128 + (ai >> 2) * 64 + (ai & 3) * 16 + quad * 4 + r;
        float v = acc[ai][bi][r] + bv;
        if (RELU) v = v > 0.f ? v : 0.f;
        if (OUTBF16) Ch[(size_t)row * N + col] = f2bf(v);
        else         Cf[(size_t)row * N + col] = v;
      }
    }
  }
}

// ---------------- MFMA flash attention ----------------
#define PADK 72
#define PADV 136
#define PADP 40
#define PADO 72

__global__ __launch_bounds__(256, 2) void attn_mfma(u16* qkv) {
  __shared__ __attribute__((aligned(16))) u16 lds[38400];   // 76.8 KB
  u16* Klds  = lds;                    // 128 x PADK = 9216
  u16* Vtlds = lds + 9216;             // 64 x PADV  = 8704

  int bid = blockIdx.x;
  int h = bid & (Hh - 1);
  int c = (bid >> 4) & (NC - 1);
  int b = bid >> 8;
  int tid = threadIdx.x, lane = tid & 63, w = tid >> 6;
  int lm = lane & 15, quad = lane >> 4;
  u16* Pw = lds + 17920 + w * 5120;

  size_t rowbase = (size_t)b * Lseq;

  s16x8 qf[4][2];
#pragma unroll
  for (int nt = 0; nt < 4; ++nt)
#pragma unroll
    for (int ks = 0; ks < 2; ++ks) {
      int qtok = c * Wc + w * 64 + nt * 16 + lm;
      qf[nt][ks] = *(const s16x8*)(qkv + (rowbase + qtok) * 3072 + h * 64 + ks * 32 + quad * 8);
    }

  fx4 acc_o[4][4] = {};
  float lsum[4] = {0.f, 0.f, 0.f, 0.f};

  int nph = (c > 0) ? 4 : 2;
  int t0  = (c > 0) ? (c - 1) * Wc : 0;

  for (int ph = 0; ph < nph; ++ph) {
    int kt0 = t0 + ph * 128;
    __syncthreads();

#pragma unroll
    for (int it = 0; it < 4; ++it) {
      int s = tid + it * 256;
      int row = s >> 3, off = (s & 7) * 8;
      uint4 kv = *(const uint4*)(qkv + (rowbase + kt0 + row) * 3072 + 1024 + h * 64 + off);
      *(uint4*)(Klds + row * PADK + off) = kv;
    }
    {
      int d = lane;
      int kb = w * 32;
      u16 tmp[32];
#pragma unroll
      for (int i = 0; i < 32; ++i)
        tmp[i] = qkv[(rowbase + kt0 + kb + i) * 3072 + 2048 + h * 64 + d];
#pragma unroll
      for (int i = 0; i < 4; ++i)
        *(uint4*)(Vtlds + d * PADV + kb + i * 8) = *(const uint4*)(tmp + i * 8);
    }
    __syncthreads();

#pragma unroll
    for (int kt = 0; kt < 4; ++kt) {
      u16* Pb = Pw + (kt & 1) * 2560;
      fx4 sa[2][4] = {};
#pragma unroll
      for (int ks = 0; ks < 2; ++ks) {
        s16x8 kf0 = *(const s16x8*)(Klds + (kt * 32 + lm) * PADK + ks * 32 + quad * 8);
        s16x8 kf1 = *(const s16x8*)(Klds + (kt * 32 + 16 + lm) * PADK + ks * 32 + quad * 8);
#pragma unroll
        for (int nt = 0; nt < 4; ++nt) {
          sa[0][nt] = __builtin_amdgcn_mfma_f32_16x16x32_bf16(kf0, qf[nt][ks], sa[0][nt], 0, 0, 0);
          sa[1][nt] = __builtin_amdgcn_mfma_f32_16x16x32_bf16(kf1, qf[nt][ks], sa[1][nt], 0, 0, 0);
        }
      }
#pragma unroll
      for (int mt = 0; mt < 2; ++mt)
#pragma unroll
        for (int nt = 0; nt < 4; ++nt) {
          float e0 = __expf(sa[mt][nt][0] * 0.125f);
          float e1 = __expf(sa[mt][nt][1] * 0.125f);
          float e2 = __expf(sa[mt][nt][2] * 0.125f);
          float e3 = __expf(sa[mt][nt][3] * 0.125f);
          lsum[nt] += (e0 + e1) + (e2 + e3);
          uint2 pk; pk.x = pack2bf(e0, e1); pk.y = pack2bf(e2, e3);
          *(uint2*)(Pb + (nt * 16 + lm) * PADP + mt * 16 + quad * 4) = pk;
        }
#pragma unroll
      for (int mt = 0; mt < 4; ++mt) {
        s16x8 vf = *(const s16x8*)(Vtlds + (mt * 16 + lm) * PADV + kt * 32 + quad * 8);
#pragma unroll
        for (int nt = 0; nt < 4; ++nt) {
          s16x8 pf = *(const s16x8*)(Pb + (nt * 16 + lm) * PADP + quad * 8);
          acc_o[mt][nt] = __builtin_amdgcn_mfma_f32_16x16x32_bf16(vf, pf, acc_o[mt][nt], 0, 0, 0);
        }
      }
    }
  }

#pragma unroll
  for (int nt = 0; nt < 4; ++nt) {
    float v = lsum[nt];
    v += __shfl_xor(v, 16, 64);
    v += __shfl_xor(v, 32, 64);
    lsum[nt] = 1.f / v;
  }

  __syncthreads();
  u16* Obuf = lds;
#pragma unroll
  for (int mt = 0; mt < 4; ++mt)
#pragma unroll
    for (int nt = 0; nt < 4; ++nt) {
      float inv = lsum[nt];
      uint2 pk;
      pk.x = pack2bf(acc_o[mt][nt][0] * inv, acc_o[mt][nt][1] * inv);
      pk.y = pack2bf(acc_o[mt][nt][2] * inv, acc_o[mt][nt][3] * inv);
      int q = nt * 16 + lm;
      *(uint2*)(Obuf + (w * 64 + q) * PADO + mt * 16 + quad * 4) = pk;
    }
  __syncthreads();
#pragma unroll
  for (int it = 0; it < 8; ++it) {
    int s = tid + it * 256;
    int row = s >> 3, chunk = s & 7;
    uint4 v = *(const uint4*)(Obuf + row * PADO + chunk * 8);
    *(uint4*)(qkv + (rowbase + c * Wc + row) * 3072 + h * 64 + chunk * 8) = v;
  }
}

// ---------------- layernorm variants ----------------
__device__ __forceinline__ void ln_core(float sx, float sy, float sz, float sw,
                                        const float* gamma, const float* beta, int tid,
                                        float* red, float4* outv) {
  float part = sx + sy + sz + sw;
#pragma unroll
  for (int off = 32; off > 0; off >>= 1) part += __shfl_down(part, off, 64);
  if ((tid & 63) == 0) red[tid >> 6] = part;
  __syncthreads();
  float mean = (red[0] + red[1] + red[2] + red[3]) * (1.f / 1024.f);
  __syncthreads();

  float dx = sx - mean, dy = sy - mean, dz = sz - mean, dw = sw - mean;
  float sq = dx * dx + dy * dy + dz * dz + dw * dw;
#pragma unroll
  for (int off = 32; off > 0; off >>= 1) sq += __shfl_down(sq, off, 64);
  if ((tid & 63) == 0) red[tid >> 6] = sq;
  __syncthreads();
  float var = (red[0] + red[1] + red[2] + red[3]) * (1.f / 1024.f);
  float rs = rsqrtf(var + 1e-6f);

  float4 g = *(const float4*)(gamma + tid * 4);
  float4 be = *(const float4*)(beta + tid * 4);
  outv->x = g.x * dx * rs + be.x;
  outv->y = g.y * dy * rs + be.y;
  outv->z = g.z * dz * rs + be.z;
  outv->w = g.w * dw * rs + be.w;
}

__global__ __launch_bounds__(256) void ln1_kernel(const float* __restrict__ r,
                                                  const float* __restrict__ dl,
                                                  const float* __restrict__ gamma,
                                                  const float* __restrict__ beta,
                                                  u16* __restrict__ outh) {
  __shared__ float red[4];
  int row = blockIdx.x, tid = threadIdx.x;
  size_t base = (size_t)row * Dm;
  float4 rv = *(const float4*)(r + base + tid * 4);
  float4 dv = *(const float4*)(dl + base + tid * 4);
  float4 o;
  ln_core(rv.x + dv.x, rv.y + dv.y, rv.z + dv.z, rv.w + dv.w, gamma, beta, tid, red, &o);
  u16 u[4] = { f2bf(o.x), f2bf(o.y), f2bf(o.z), f2bf(o.w) };
  *(uint2*)(outh + base + tid * 4) = *(const uint2*)u;
}

// LN2: sum = bf16 x1 + f32 y2 + colbias (bf2); -> f32 out (in-place ok)
__global__ __launch_bounds__(256) void ln2_kernel(const u16* __restrict__ r,
                                                  const float* dl,
                                                  const float* __restrict__ colbias,
                                                  const float* __restrict__ gamma,
                                                  const float* __restrict__ beta,
                                                  float* outf) {
  __shared__ float red[4];
  int row = blockIdx.x, tid = threadIdx.x;
  size_t base = (size_t)row * Dm;
  uint2 ru = *(const uint2*)(r + base + tid * 4);
  const u16* pu = (const u16*)&ru;
  float4 dv = *(const float4*)(dl + base + tid * 4);
  float4 bb = *(const float4*)(colbias + tid * 4);
  float4 o;
  ln_core(bf2f(pu[0]) + dv.x + bb.x, bf2f(pu[1]) + dv.y + bb.y,
          bf2f(pu[2]) + dv.z + bb.z, bf2f(pu[3]) + dv.w + bb.w,
          gamma, beta, tid, red, &o);
  *(float4*)(outf + base + tid * 4) = o;
}

// ---------------- launch ----------------
extern "C" void kernel_launch(void* const* d_in, const int* in_sizes, int n_in,
                              void* d_out, int out_size, void* d_ws, size_t ws_size,
                              hipStream_t stream) {
  const float* x         = (const float*)d_in[0];
  const float* in_proj_w = (const float*)d_in[1];
  const float* in_proj_b = (const float*)d_in[2];
  const float* out_w     = (const float*)d_in[3];
  const float* out_b     = (const float*)d_in[4];
  const float* gamma1    = (const float*)d_in[5];
  const float* beta1     = (const float*)d_in[6];
  const float* w1        = (const float*)d_in[7];
  const float* bf1       = (const float*)d_in[8];
  const float* w2        = (const float*)d_in[9];
  const float* bf2       = (const float*)d_in[10];
  const float* gamma2    = (const float*)d_in[11];
  const float* beta2     = (const float*)d_in[12];
  float* out = (float*)d_out;

  char* ws = (char*)d_ws;
  size_t off = 0;
  auto alloc = [&](size_t bytes) -> char* {
    char* p = ws + off;
    off += (bytes + 255) & ~(size_t)255;
    return p;
  };
  u16* wqkvh = (u16*)alloc((size_t)3 * Dm * Dm * 2);
  u16* owh   = (u16*)alloc((size_t)Dm * Dm * 2);
  u16* w1th  = (u16*)alloc((size_t)FFd * Dm * 2);
  u16* w2th  = (u16*)alloc((size_t)Dm * FFd * 2);
  u16* big   = (u16*)alloc((size_t)NTOK * FFd * 2);
  u16* x1h   = (u16*)alloc((size_t)NTOK * Dm * 2);
  u16* qkvh = big;
  u16* hh   = big;
  u16* xh   = (u16*)d_out;
  float* attnf = out;
  float* y2f   = out;

  cvt_f32_bf16<<<(long)NTOK * Dm / 1024, 256, 0, stream>>>(x, xh, (long)NTOK * Dm);
  cvt_f32_bf16<<<(long)3 * Dm * Dm / 1024, 256, 0, stream>>>(in_proj_w, wqkvh, (long)3 * Dm * Dm);
  cvt_f32_bf16<<<(long)Dm * Dm / 1024, 256, 0, stream>>>(out_w, owh, (long)Dm * Dm);
  transpose_f32_bf16<<<dim3(FFd / 32, Dm / 32), 256, 0, stream>>>(w1, w1th, Dm, FFd);
  transpose_f32_bf16<<<dim3(Dm / 32, FFd / 32), 256, 0, stream>>>(w2, w2th, FFd, Dm);

  // QKV projection: [16384,1024] x [3072,1024]^T -> bf16 [16384,3072]
  gemm256<0, 1, 1><<<dim3(3 * Dm / 256, NTOK / 256), 512, 0, stream>>>(
      xh, Dm, wqkvh, in_proj_b, qkvh, NTOK, 3 * Dm, Dm);

  attn_mfma<<<Bsz * NC * Hh, 256, 0, stream>>>(qkvh);

  // out projection: attn-out (qkv cols 0..1023) x out_w^T -> f32
  gemm256<0, 0, 1><<<dim3(Dm / 256, NTOK / 256), 512, 0, stream>>>(
      qkvh, 3 * Dm, owh, out_b, attnf, NTOK, Dm, Dm);

  ln1_kernel<<<NTOK, 256, 0, stream>>>(x, attnf, gamma1, beta1, x1h);

  // FFN1 + ReLU -> bf16 [16384,4096]
  gemm256<1, 1, 1><<<dim3(FFd / 256, NTOK / 256), 512, 0, stream>>>(
      x1h, Dm, w1th, bf1, hh, NTOK, FFd, Dm);

  // FFN2 -> f32 (bias bf2 folded into LN2); no split-K, no atomics
  gemm256<0, 0, 0><<<dim3(Dm / 256, NTOK / 256), 512, 0, stream>>>(
      hh, FFd, w2th, (const float*)nullptr, y2f, NTOK, Dm, FFd);

  ln2_kernel<<<NTOK, 256, 0, stream>>>(x1h, y2f, bf2, gamma2, beta2, out);
}

// Round 4
// 688.543 us; speedup vs baseline: 1.2701x; 1.0045x over previous
//
#include <hip/hip_runtime.h>
#include <stdint.h>

#define Bsz 4
#define Lseq 4096
#define Dm 1024
#define Hh 16
#define Wc 256
#define FFd 4096
#define NC 16
#define NTOK (Bsz * Lseq)   // 16384

typedef unsigned short u16;

__device__ __forceinline__ float bf2f(u16 u) {
  union { unsigned int i; float f; } v; v.i = ((unsigned int)u) << 16; return v.f;
}
__device__ __forceinline__ u16 f2bf(float f) {
  union { float f; unsigned int i; } v; v.f = f;
  unsigned int r = v.i + 0x7fffu + ((v.i >> 16) & 1u);
  return (u16)(r >> 16);
}
__device__ __forceinline__ unsigned int pack2bf(float a, float b) {
  union { float f; unsigned int u; } x, y; x.f = a; y.f = b;
  return ((x.u + 0x8000u) >> 16) | ((y.u + 0x8000u) & 0xffff0000u);
}

// ---------------- utility kernels ----------------
__global__ void cvt_f32_bf16(const float* __restrict__ in, u16* __restrict__ out, long n) {
  long i = ((long)blockIdx.x * blockDim.x + threadIdx.x) * 4;
  if (i >= n) return;
  float4 v = *(const float4*)(in + i);
  u16 o[4] = { f2bf(v.x), f2bf(v.y), f2bf(v.z), f2bf(v.w) };
  *(uint2*)(out + i) = *(const uint2*)o;
}

__global__ void transpose_f32_bf16(const float* __restrict__ in, u16* __restrict__ out,
                                   int R, int C) {
  __shared__ float tile[32][33];
  int tx = threadIdx.x & 31, ty = threadIdx.x >> 5;       // 32 x 8
  int r0 = blockIdx.y * 32, c0 = blockIdx.x * 32;
#pragma unroll
  for (int k = 0; k < 4; ++k)
    tile[ty + 8 * k][tx] = in[(size_t)(r0 + ty + 8 * k) * C + c0 + tx];
  __syncthreads();
#pragma unroll
  for (int k = 0; k < 4; ++k)
    out[(size_t)(c0 + ty + 8 * k) * R + r0 + tx] = f2bf(tile[tx][ty + 8 * k]);
}

// ---------------- GEMM: 256x256 tile, BK=64, pipelined 4-phase schedule ----
typedef __attribute__((ext_vector_type(8))) short s16x8;
typedef __attribute__((ext_vector_type(4))) float fx4;
typedef __attribute__((address_space(1))) unsigned int as1u;
typedef __attribute__((address_space(3))) unsigned int as3u;
typedef __attribute__((address_space(3))) const u16 l16c;

__device__ __forceinline__ void gll16(const void* g, void* l) {
  __builtin_amdgcn_global_load_lds((as1u*)g, (as3u*)l, 16, 0, 0);
}

// ds_read_b128 with literal immediate offset from a precomputed base VGPR.
// Invisible to the compiler's alias/waitcnt machinery; consumers are gated by
// explicit s_waitcnt lgkmcnt(0) + sched_barrier(0) (rule #18).
#define DSR(dst, base, IMM)                                                 \
  asm volatile("ds_read_b128 %0, %1 offset:" IMM : "=v"(dst) : "v"(base))

// XCD-partition swizzle: xcd = flat % 8. Row-blocks partitioned by mb%8==xcd,
// column-outer within an XCD so consecutive same-XCD blocks share a B-strip.
__device__ __forceinline__ void swizzle_mn(int MB, int NB, int* mb, int* nb) {
  int flat = blockIdx.y * NB + blockIdx.x;
  if ((MB & 7) == 0) {
    int xcd = flat & 7;
    int j = flat >> 3;
    int rpx = MB >> 3;
    *nb = j / rpx;
    int rowin = j - *nb * rpx;
    *mb = (rowin << 3) | xcd;
  } else {
    *mb = blockIdx.y; *nb = blockIdx.x;
  }
}

// Stage one 16KB half-tile segment: 16 wave-loads of 8 rows x 64 cols (1KB each).
// LDS dest is LINEAR [256][64] bf16; bank-swizzle is applied by permuting the
// GLOBAL source chunk (rule #21): phys chunk c holds logical chunk c ^ (row&7).
__device__ __forceinline__ void stage_seg(const u16* __restrict__ G, int ld, int k0,
                                          u16* L, int rb0, int rb1,
                                          int wid, int lane) {
#pragma unroll
  for (int i = 0; i < 2; ++i) {
    int j = wid * 2 + i;
    int rs = (j < 8) ? (rb0 + j * 8) : (rb1 + (j - 8) * 8);   // wave-uniform
    int grow = rs + (lane >> 3);
    int gcol = k0 + (((lane & 7) ^ (lane >> 3)) << 3);
    gll16(G + (size_t)grow * ld + gcol, L + rs * 64);
  }
}

#define MFMA_Q(MQ, NQ)                                                           \
  {                                                                              \
    _Pragma("unroll") for (int mt = 0; mt < 4; ++mt) {                           \
      _Pragma("unroll") for (int nt = 0; nt < 2; ++nt) {                         \
        acc[(MQ)*4 + mt][(NQ)*2 + nt] = __builtin_amdgcn_mfma_f32_16x16x32_bf16( \
            af[mt][0], bfr[NQ][nt][0], acc[(MQ)*4 + mt][(NQ)*2 + nt], 0, 0, 0);  \
        acc[(MQ)*4 + mt][(NQ)*2 + nt] = __builtin_amdgcn_mfma_f32_16x16x32_bf16( \
            af[mt][1], bfr[NQ][nt][1], acc[(MQ)*4 + mt][(NQ)*2 + nt], 0, 0, 0);  \
      }                                                                          \
    }                                                                            \
  }

#define WAIT_LGKM_FENCE()                                  \
  asm volatile("s_waitcnt lgkmcnt(0)" ::: "memory");       \
  __builtin_amdgcn_sched_barrier(0);

#define SB() __builtin_amdgcn_sched_barrier(0);

// read-issue bundles (volatile asm; hand-unrolled literal offsets)
#define R_A_MQ0()                     \
  DSR(af[0][0], baseA0, "0");         \
  DSR(af[0][1], baseA1, "0");         \
  DSR(af[1][0], baseA0, "2048");      \
  DSR(af[1][1], baseA1, "2048");      \
  DSR(af[2][0], baseA0, "4096");      \
  DSR(af[2][1], baseA1, "4096");      \
  DSR(af[3][0], baseA0, "6144");      \
  DSR(af[3][1], baseA1, "6144");
#define R_A_MQ1()                     \
  DSR(af[0][0], baseA0, "8192");      \
  DSR(af[0][1], baseA1, "8192");      \
  DSR(af[1][0], baseA0, "10240");     \
  DSR(af[1][1], baseA1, "10240");     \
  DSR(af[2][0], baseA0, "12288");     \
  DSR(af[2][1], baseA1, "12288");     \
  DSR(af[3][0], baseA0, "14336");     \
  DSR(af[3][1], baseA1, "14336");
#define R_B_SEG0()                    \
  DSR(bfr[0][0][0], baseB0, "0");     \
  DSR(bfr[0][0][1], baseB1, "0");     \
  DSR(bfr[0][1][0], baseB0, "2048");  \
  DSR(bfr[0][1][1], baseB1, "2048");
#define R_B_SEG1()                    \
  DSR(bfr[1][0][0], baseB0, "4096");  \
  DSR(bfr[1][0][1], baseB1, "4096");  \
  DSR(bfr[1][1][0], baseB0, "6144");  \
  DSR(bfr[1][1][1], baseB1, "6144");

// C[M,N] = A[M,K](bf16, row stride lda) * B[N,K](bf16)^T (+bias). 512 threads,
// 8 waves in 2(M) x 4(N); per-wave output 128x64. 128 KiB LDS, 2 K-tile dbuf.
// Pipelined rhythm: each phase's ds_reads are issued in the PREVIOUS phase's
// MFMA shadow (same fragment regs; WAR handled by HW hazard pass, order pinned
// by sched_barrier). lgkmcnt(0) then waits on ~1-phase-old reads -> no stall.
//   ph1: MFMA(0,0); issue bfr1          ph2: MFMA(0,1); issue af-mq1
//   ph3: MFMA(1,1); (no reads)          ph4: vmcnt(4); MFMA(1,0); toggle;
//                                            issue af-mq0 + bfr0 of t+1
// Staging: B(t+1) s0/s1 at ph1/ph2 (other buffer); A(t+2) s0/s1 at ph3/ph4
// (current buffer, regions dead since ph4(t-1)/ph2(t) reads completed).
template <int RELU, int OUTBF16, int HASBIAS>
__global__ __launch_bounds__(512, 2) void gemm256(const u16* A, int lda,
                                                  const u16* Bm,
                                                  const float* __restrict__ bias,
                                                  void* Cp,
                                                  int M, int N, int K) {
  __shared__ __attribute__((aligned(16))) u16 As[2][256 * 64];
  __shared__ __attribute__((aligned(16))) u16 Bs[2][256 * 64];
  int tid = threadIdx.x;
  int lane = tid & 63, wid = tid >> 6;
  int lm = lane & 15, quad = lane >> 4;
  int wr = wid >> 2, wc = wid & 3;
  int mb, nb;
  swizzle_mn(gridDim.y, gridDim.x, &mb, &nb);
  int m0 = mb * 256, n0 = nb * 256;
  const u16* Ag = A + (size_t)m0 * lda;
  const u16* Bg = Bm + (size_t)n0 * K;
  int NT = K >> 6;

  // swizzled read offsets (elements): logical chunk (ks*4+quad) ^ (row&7), row&7==lm&7
  int off0 = (quad ^ (lm & 7)) << 3;
  int off1 = ((4 + quad) ^ (lm & 7)) << 3;

  // precomputed LDS byte-address bases (buffer 0); +offset: immediates walk frags
  unsigned ldsA = (unsigned)(size_t)(l16c*)(&As[0][0]);
  unsigned ldsB = (unsigned)(size_t)(l16c*)(&Bs[0][0]);
  unsigned baseA0 = ldsA + (unsigned)(((wr * 128 + lm) * 64 + off0) * 2);
  unsigned baseA1 = ldsA + (unsigned)(((wr * 128 + lm) * 64 + off1) * 2);
  unsigned baseB0 = ldsB + (unsigned)(((wc * 64 + lm) * 64 + off0) * 2);
  unsigned baseB1 = ldsB + (unsigned)(((wc * 64 + lm) * 64 + off1) * 2);
  int sel = 32768;   // buffer toggle delta (bytes); sign alternates

  fx4 acc[8][4] = {};

  // prologue: tile0 A+B, tile1 A. vmcnt(4) -> tile0 landed, tile1-A in flight.
  stage_seg(Ag, lda, 0, As[0], 0, 128, wid, lane);
  stage_seg(Ag, lda, 0, As[0], 64, 192, wid, lane);
  stage_seg(Bg, K, 0, Bs[0], 0, 64, wid, lane);
  stage_seg(Bg, K, 0, Bs[0], 128, 192, wid, lane);
  if (NT > 1) {
    stage_seg(Ag, lda, 64, As[1], 0, 128, wid, lane);
    stage_seg(Ag, lda, 64, As[1], 64, 192, wid, lane);
    asm volatile("s_waitcnt vmcnt(4)" ::: "memory");
  } else {
    asm volatile("s_waitcnt vmcnt(0)" ::: "memory");
  }
  __builtin_amdgcn_s_barrier();

  s16x8 af[4][2];
  s16x8 bfr[2][2][2];

  // pre-issue ph1(t=0) operand reads (buf0)
  R_A_MQ0();
  R_B_SEG0();

  for (int t = 0; t < NT; ++t) {
    u16* Bn = Bs[(t + 1) & 1];
    u16* An2 = As[t & 1];        // t+2 has same parity
    int kn = (t + 1) << 6, kn2 = (t + 2) << 6;

    // ---- phase 1: MFMA (mq0,nq0); stage B(t+1) s0; issue bfr1 reads
    if (t + 1 < NT) stage_seg(Bg, K, kn, Bn, 0, 64, wid, lane);
    __builtin_amdgcn_s_barrier();
    WAIT_LGKM_FENCE()
    __builtin_amdgcn_s_setprio(1);
    MFMA_Q(0, 0)
    __builtin_amdgcn_s_setprio(0);
    SB()
    R_B_SEG1();
    __builtin_amdgcn_s_barrier();

    // ---- phase 2: MFMA (mq0,nq1); stage B(t+1) s1; issue af-mq1 reads
    if (t + 1 < NT) stage_seg(Bg, K, kn, Bn, 128, 192, wid, lane);
    __builtin_amdgcn_s_barrier();
    WAIT_LGKM_FENCE()
    __builtin_amdgcn_s_setprio(1);
    MFMA_Q(0, 1)
    __builtin_amdgcn_s_setprio(0);
    SB()
    R_A_MQ1();
    __builtin_amdgcn_s_barrier();

    // ---- phase 3: MFMA (mq1,nq1); stage A(t+2) s0 (rows dead since ph4(t-1))
    if (t + 2 < NT) stage_seg(Ag, lda, kn2, An2, 0, 128, wid, lane);
    __builtin_amdgcn_s_barrier();
    WAIT_LGKM_FENCE()
    __builtin_amdgcn_s_setprio(1);
    MFMA_Q(1, 1)
    __builtin_amdgcn_s_setprio(0);
    SB()
    __builtin_amdgcn_s_barrier();

    // ---- phase 4: stage A(t+2) s1; boundary vmcnt; MFMA (mq1,nq0);
    //      toggle bases; issue t+1's af-mq0 + bfr0 reads (buf t+1, just landed)
    if (t + 2 < NT) {
      stage_seg(Ag, lda, kn2, An2, 64, 192, wid, lane);
      asm volatile("s_waitcnt vmcnt(4)" ::: "memory");
    } else if (t + 2 == NT) {
      asm volatile("s_waitcnt vmcnt(0)" ::: "memory");
    }
    __builtin_amdgcn_s_barrier();
    __builtin_amdgcn_s_setprio(1);
    MFMA_Q(1, 0)
    __builtin_amdgcn_s_setprio(0);
    SB()
    baseA0 += sel; baseA1 += sel; baseB0 += sel; baseB1 += sel; sel = -sel;
    if (t + 1 < NT) {
      R_A_MQ0();
      R_B_SEG0();
    }
    __builtin_amdgcn_s_barrier();
  }

  // epilogue
  float* Cf = (float*)Cp;
  u16* Ch = (u16*)Cp;
#pragma unroll
  for (int ai = 0; ai < 8; ++ai) {
#pragma unroll
    for (int bi = 0; bi < 4; ++bi) {
      int col = n0 + wc * 64 + (bi >> 1) * 32 + (bi & 1) * 16 + lm;
      float bv = HASBIAS ? bias[col] : 0.f;
#pragma unroll
      for (int r = 0; r < 4; ++r) {
        int row = m0 + wr * 128 + (ai >> 2) * 64 + (ai & 3) * 16 + quad * 4 + r;
        float v = acc[ai][bi][r] + bv;
        if (RELU) v = v > 0.f ? v : 0.f;
        if (OUTBF16) Ch[(size_t)row * N + col] = f2bf(v);
        else         Cf[(size_t)row * N + col] = v;
      }
    }
  }
}

// ---------------- MFMA flash attention ----------------
#define PADK 72
#define PADV 136
#define PADP 40
#define PADO 72

__global__ __launch_bounds__(256, 2) void attn_mfma(u16* qkv) {
  __shared__ __attribute__((aligned(16))) u16 lds[38400];   // 76.8 KB
  u16* Klds  = lds;                    // 128 x PADK = 9216
  u16* Vtlds = lds + 9216;             // 64 x PADV  = 8704

  int bid = blockIdx.x;
  int h = bid & (Hh - 1);
  int c = (bid >> 4) & (NC - 1);
  int b = bid >> 8;
  int tid = threadIdx.x, lane = tid & 63, w = tid >> 6;
  int lm = lane & 15, quad = lane >> 4;
  u16* Pw = lds + 17920 + w * 5120;

  size_t rowbase = (size_t)b * Lseq;

  s16x8 qf[4][2];
#pragma unroll
  for (int nt = 0; nt < 4; ++nt)
#pragma unroll
    for (int ks = 0; ks < 2; ++ks) {
      int qtok = c * Wc + w * 64 + nt * 16 + lm;
      qf[nt][ks] = *(const s16x8*)(qkv + (rowbase + qtok) * 3072 + h * 64 + ks * 32 + quad * 8);
    }

  fx4 acc_o[4][4] = {};
  float lsum[4] = {0.f, 0.f, 0.f, 0.f};

  int nph = (c > 0) ? 4 : 2;
  int t0  = (c > 0) ? (c - 1) * Wc : 0;

  for (int ph = 0; ph < nph; ++ph) {
    int kt0 = t0 + ph * 128;
    __syncthreads();

#pragma unroll
    for (int it = 0; it < 4; ++it) {
      int s = tid + it * 256;
      int row = s >> 3, off = (s & 7) * 8;
      uint4 kv = *(const uint4*)(qkv + (rowbase + kt0 + row) * 3072 + 1024 + h * 64 + off);
      *(uint4*)(Klds + row * PADK + off) = kv;
    }
    {
      int d = lane;
      int kb = w * 32;
      u16 tmp[32];
#pragma unroll
      for (int i = 0; i < 32; ++i)
        tmp[i] = qkv[(rowbase + kt0 + kb + i) * 3072 + 2048 + h * 64 + d];
#pragma unroll
      for (int i = 0; i < 4; ++i)
        *(uint4*)(Vtlds + d * PADV + kb + i * 8) = *(const uint4*)(tmp + i * 8);
    }
    __syncthreads();

#pragma unroll
    for (int kt = 0; kt < 4; ++kt) {
      u16* Pb = Pw + (kt & 1) * 2560;
      fx4 sa[2][4] = {};
#pragma unroll
      for (int ks = 0; ks < 2; ++ks) {
        s16x8 kf0 = *(const s16x8*)(Klds + (kt * 32 + lm) * PADK + ks * 32 + quad * 8);
        s16x8 kf1 = *(const s16x8*)(Klds + (kt * 32 + 16 + lm) * PADK + ks * 32 + quad * 8);
#pragma unroll
        for (int nt = 0; nt < 4; ++nt) {
          sa[0][nt] = __builtin_amdgcn_mfma_f32_16x16x32_bf16(kf0, qf[nt][ks], sa[0][nt], 0, 0, 0);
          sa[1][nt] = __builtin_amdgcn_mfma_f32_16x16x32_bf16(kf1, qf[nt][ks], sa[1][nt], 0, 0, 0);
        }
      }
#pragma unroll
      for (int mt = 0; mt < 2; ++mt)
#pragma unroll
        for (int nt = 0; nt < 4; ++nt) {
          float e0 = __expf(sa[mt][nt][0] * 0.125f);
          float e1 = __expf(sa[mt][nt][1] * 0.125f);
          float e2 = __expf(sa[mt][nt][2] * 0.125f);
          float e3 = __expf(sa[mt][nt][3] * 0.125f);
          lsum[nt] += (e0 + e1) + (e2 + e3);
          uint2 pk; pk.x = pack2bf(e0, e1); pk.y = pack2bf(e2, e3);
          *(uint2*)(Pb + (nt * 16 + lm) * PADP + mt * 16 + quad * 4) = pk;
        }
#pragma unroll
      for (int mt = 0; mt < 4; ++mt) {
        s16x8 vf = *(const s16x8*)(Vtlds + (mt * 16 + lm) * PADV + kt * 32 + quad * 8);
#pragma unroll
        for (int nt = 0; nt < 4; ++nt) {
          s16x8 pf = *(const s16x8*)(Pb + (nt * 16 + lm) * PADP + quad * 8);
          acc_o[mt][nt] = __builtin_amdgcn_mfma_f32_16x16x32_bf16(vf, pf, acc_o[mt][nt], 0, 0, 0);
        }
      }
    }
  }

#pragma unroll
  for (int nt = 0; nt < 4; ++nt) {
    float v = lsum[nt];
    v += __shfl_xor(v, 16, 64);
    v += __shfl_xor(v, 32, 64);
    lsum[nt] = 1.f / v;
  }

  __syncthreads();
  u16* Obuf = lds;
#pragma unroll
  for (int mt = 0; mt < 4; ++mt)
#pragma unroll
    for (int nt = 0; nt < 4; ++nt) {
      float inv = lsum[nt];
      uint2 pk;
      pk.x = pack2bf(acc_o[mt][nt][0] * inv, acc_o[mt][nt][1] * inv);
      pk.y = pack2bf(acc_o[mt][nt][2] * inv, acc_o[mt][nt][3] * inv);
      int q = nt * 16 + lm;
      *(uint2*)(Obuf + (w * 64 + q) * PADO + mt * 16 + quad * 4) = pk;
    }
  __syncthreads();
#pragma unroll
  for (int it = 0; it < 8; ++it) {
    int s = tid + it * 256;
    int row = s >> 3, chunk = s & 7;
    uint4 v = *(const uint4*)(Obuf + row * PADO + chunk * 8);
    *(uint4*)(qkv + (rowbase + c * Wc + row) * 3072 + h * 64 + chunk * 8) = v;
  }
}

// ---------------- layernorm variants ----------------
__device__ __forceinline__ void ln_core(float sx, float sy, float sz, float sw,
                                        const float* gamma, const float* beta, int tid,
                                        float* red, float4* outv) {
  float part = sx + sy + sz + sw;
#pragma unroll
  for (int off = 32; off > 0; off >>= 1) part += __shfl_down(part, off, 64);
  if ((tid & 63) == 0) red[tid >> 6] = part;
  __syncthreads();
  float mean = (red[0] + red[1] + red[2] + red[3]) * (1.f / 1024.f);
  __syncthreads();

  float dx = sx - mean, dy = sy - mean, dz = sz - mean, dw = sw - mean;
  float sq = dx * dx + dy * dy + dz * dz + dw * dw;
#pragma unroll
  for (int off = 32; off > 0; off >>= 1) sq += __shfl_down(sq, off, 64);
  if ((tid & 63) == 0) red[tid >> 6] = sq;
  __syncthreads();
  float var = (red[0] + red[1] + red[2] + red[3]) * (1.f / 1024.f);
  float rs = rsqrtf(var + 1e-6f);

  float4 g = *(const float4*)(gamma + tid * 4);
  float4 be = *(const float4*)(beta + tid * 4);
  outv->x = g.x * dx * rs + be.x;
  outv->y = g.y * dy * rs + be.y;
  outv->z = g.z * dz * rs + be.z;
  outv->w = g.w * dw * rs + be.w;
}

__global__ __launch_bounds__(256) void ln1_kernel(const float* __restrict__ r,
                                                  const float* __restrict__ dl,
                                                  const float* __restrict__ gamma,
                                                  const float* __restrict__ beta,
                                                  u16* __restrict__ outh) {
  __shared__ float red[4];
  int row = blockIdx.x, tid = threadIdx.x;
  size_t base = (size_t)row * Dm;
  float4 rv = *(const float4*)(r + base + tid * 4);
  float4 dv = *(const float4*)(dl + base + tid * 4);
  float4 o;
  ln_core(rv.x + dv.x, rv.y + dv.y, rv.z + dv.z, rv.w + dv.w, gamma, beta, tid, red, &o);
  u16 u[4] = { f2bf(o.x), f2bf(o.y), f2bf(o.z), f2bf(o.w) };
  *(uint2*)(outh + base + tid * 4) = *(const uint2*)u;
}

// LN2: sum = bf16 x1 + f32 y2 + colbias (bf2); -> f32 out (in-place ok)
__global__ __launch_bounds__(256) void ln2_kernel(const u16* __restrict__ r,
                                                  const float* dl,
                                                  const float* __restrict__ colbias,
                                                  const float* __restrict__ gamma,
                                                  const float* __restrict__ beta,
                                                  float* outf) {
  __shared__ float red[4];
  int row = blockIdx.x, tid = threadIdx.x;
  size_t base = (size_t)row * Dm;
  uint2 ru = *(const uint2*)(r + base + tid * 4);
  const u16* pu = (const u16*)&ru;
  float4 dv = *(const float4*)(dl + base + tid * 4);
  float4 bb = *(const float4*)(colbias + tid * 4);
  float4 o;
  ln_core(bf2f(pu[0]) + dv.x + bb.x, bf2f(pu[1]) + dv.y + bb.y,
          bf2f(pu[2]) + dv.z + bb.z, bf2f(pu[3]) + dv.w + bb.w,
          gamma, beta, tid, red, &o);
  *(float4*)(outf + base + tid * 4) = o;
}

// ---------------- launch ----------------
extern "C" void kernel_launch(void* const* d_in, const int* in_sizes, int n_in,
                              void* d_out, int out_size, void* d_ws, size_t ws_size,
                              hipStream_t stream) {
  const float* x         = (const float*)d_in[0];
  const float* in_proj_w = (const float*)d_in[1];
  const float* in_proj_b = (const float*)d_in[2];
  const float* out_w     = (const float*)d_in[3];
  const float* out_b     = (const float*)d_in[4];
  const float* gamma1    = (const float*)d_in[5];
  const float* beta1     = (const float*)d_in[6];
  const float* w1        = (const float*)d_in[7];
  const float* bf1       = (const float*)d_in[8];
  const float* w2        = (const float*)d_in[9];
  const float* bf2       = (const float*)d_in[10];
  const float* gamma2    = (const float*)d_in[11];
  const float* beta2     = (const float*)d_in[12];
  float* out = (float*)d_out;

  char* ws = (char*)d_ws;
  size_t off = 0;
  auto alloc = [&](size_t bytes) -> char* {
    char* p = ws + off;
    off += (bytes + 255) & ~(size_t)255;
    return p;
  };
  u16* wqkvh = (u16*)alloc((size_t)3 * Dm * Dm * 2);
  u16* owh   = (u16*)alloc((size_t)Dm * Dm * 2);
  u16* w1th  = (u16*)alloc((size_t)FFd * Dm * 2);
  u16* w2th  = (u16*)alloc((size_t)Dm * FFd * 2);
  u16* big   = (u16*)alloc((size_t)NTOK * FFd * 2);
  u16* x1h   = (u16*)alloc((size_t)NTOK * Dm * 2);
  u16* qkvh = big;
  u16* hh   = big;
  u16* xh   = (u16*)d_out;
  float* attnf = out;
  float* y2f   = out;

  cvt_f32_bf16<<<(long)NTOK * Dm / 1024, 256, 0, stream>>>(x, xh, (long)NTOK * Dm);
  cvt_f32_bf16<<<(long)3 * Dm * Dm / 1024, 256, 0, stream>>>(in_proj_w, wqkvh, (long)3 * Dm * Dm);
  cvt_f32_bf16<<<(long)Dm * Dm / 1024, 256, 0, stream>>>(out_w, owh, (long)Dm * Dm);
  transpose_f32_bf16<<<dim3(FFd / 32, Dm / 32), 256, 0, stream>>>(w1, w1th, Dm, FFd);
  transpose_f32_bf16<<<dim3(Dm / 32, FFd / 32), 256, 0, stream>>>(w2, w2th, FFd, Dm);

  // QKV projection: [16384,1024] x [3072,1024]^T -> bf16 [16384,3072]
  gemm256<0, 1, 1><<<dim3(3 * Dm / 256, NTOK / 256), 512, 0, stream>>>(
      xh, Dm, wqkvh, in_proj_b, qkvh, NTOK, 3 * Dm, Dm);

  attn_mfma<<<Bsz * NC * Hh, 256, 0, stream>>>(qkvh);

  // out projection: attn-out (qkv cols 0..1023) x out_w^T -> f32
  gemm256<0, 0, 1><<<dim3(Dm / 256, NTOK / 256), 512, 0, stream>>>(
      qkvh, 3 * Dm, owh, out_b, attnf, NTOK, Dm, Dm);

  ln1_kernel<<<NTOK, 256, 0, stream>>>(x, attnf, gamma1, beta1, x1h);

  // FFN1 + ReLU -> bf16 [16384,4096]
  gemm256<1, 1, 1><<<dim3(FFd / 256, NTOK / 256), 512, 0, stream>>>(
      x1h, Dm, w1th, bf1, hh, NTOK, FFd, Dm);

  // FFN2 -> f32 (bias bf2 folded into LN2); no split-K, no atomics
  gemm256<0, 0, 0><<<dim3(Dm / 256, NTOK / 256), 512, 0, stream>>>(
      hh, FFd, w2th, (const float*)nullptr, y2f, NTOK, Dm, FFd);

  ln2_kernel<<<NTOK, 256, 0, stream>>>(x1h, y2f, bf2, gamma2, beta2, out);
}

// Round 5
// 679.137 us; speedup vs baseline: 1.2877x; 1.0138x over previous
//
#include <hip/hip_runtime.h>
#include <stdint.h>

#define Bsz 4
#define Lseq 4096
#define Dm 1024
#define Hh 16
#define Wc 256
#define FFd 4096
#define NC 16
#define NTOK (Bsz * Lseq)   // 16384

typedef unsigned short u16;

__device__ __forceinline__ float bf2f(u16 u) {
  union { unsigned int i; float f; } v; v.i = ((unsigned int)u) << 16; return v.f;
}
__device__ __forceinline__ u16 f2bf(float f) {
  union { float f; unsigned int i; } v; v.f = f;
  unsigned int r = v.i + 0x7fffu + ((v.i >> 16) & 1u);
  return (u16)(r >> 16);
}
__device__ __forceinline__ unsigned int pack2bf(float a, float b) {
  union { float f; unsigned int u; } x, y; x.f = a; y.f = b;
  return ((x.u + 0x8000u) >> 16) | ((y.u + 0x8000u) & 0xffff0000u);
}

// ---------------- utility kernels ----------------
__global__ void cvt_f32_bf16(const float* __restrict__ in, u16* __restrict__ out, long n) {
  long i = ((long)blockIdx.x * blockDim.x + threadIdx.x) * 4;
  if (i >= n) return;
  float4 v = *(const float4*)(in + i);
  u16 o[4] = { f2bf(v.x), f2bf(v.y), f2bf(v.z), f2bf(v.w) };
  *(uint2*)(out + i) = *(const uint2*)o;
}

// ---- weight packing into MFMA-fragment order ----
// Packed layout: chunk c = ((t*(N/16)+g)*2+ks) of 512 u16; element c*512 + lane*8,
// lane = quad*16+lm, holding B[n = g*16+lm][k = t*64 + ks*32 + quad*8 .. +8].
// A wave's fragment load = one contiguous 1KB chunk.

// W [N,K] f32 row-major -> packed bf16
__global__ void pack_f32_nk(const float* __restrict__ W, u16* __restrict__ P, int N, int K) {
  long idx = (long)blockIdx.x * 256 + threadIdx.x;     // one 8-elem group per thread
  int lane = (int)(idx & 63);
  long c = idx >> 6;
  int ks = (int)(c & 1);
  long c2 = c >> 1;
  int g = (int)(c2 % (N >> 4));
  int t = (int)(c2 / (N >> 4));
  int n = g * 16 + (lane & 15);
  int k = t * 64 + ks * 32 + (lane >> 4) * 8;
  const float* src = W + (size_t)n * K + k;
  u16 o[8];
#pragma unroll
  for (int e = 0; e < 8; ++e) o[e] = f2bf(src[e]);
  *(uint4*)(P + idx * 8) = *(const uint4*)o;
}

// W [K,N] f32 row-major (so B = W^T, [N,K]) -> packed bf16. grid (N/32, K/64), 256 thr.
__global__ void transpose_pack_f32(const float* __restrict__ W, u16* __restrict__ P,
                                   int N, int K) {
  __shared__ float t64[64][33];
  int tid = threadIdx.x;
  int n0 = blockIdx.x * 32, k0 = blockIdx.y * 64;
  int tx = tid & 31, ty = tid >> 5;   // 32 x 8
#pragma unroll
  for (int p = 0; p < 8; ++p)
    t64[ty + 8 * p][tx] = W[(size_t)(k0 + ty + 8 * p) * N + n0 + tx];
  __syncthreads();
  int nl = tid & 31, kq = tid >> 5;       // group: n-local 0..31, k-octet 0..7
  int ks = kq >> 2, quad = kq & 3;
  int g = (n0 >> 4) + (nl >> 4);
  int lmv = nl & 15;
  int t = k0 >> 6;
  u16 o[8];
#pragma unroll
  for (int e = 0; e < 8; ++e) o[e] = f2bf(t64[kq * 8 + e][nl]);
  size_t c = ((size_t)t * (N >> 4) + g) * 2 + ks;
  *(uint4*)(P + c * 512 + (quad * 16 + lmv) * 8) = *(const uint4*)o;
}

// ---------------- GEMM: 256x256 tile, BK=64, A-in-LDS(4-ring) + B-from-global ----
typedef __attribute__((ext_vector_type(8))) short s16x8;
typedef __attribute__((ext_vector_type(4))) float fx4;
typedef __attribute__((address_space(1))) unsigned int as1u;
typedef __attribute__((address_space(3))) unsigned int as3u;
typedef __attribute__((address_space(3))) const u16 l16c;

__device__ __forceinline__ void gll16(const void* g, void* l) {
  __builtin_amdgcn_global_load_lds((as1u*)g, (as3u*)l, 16, 0, 0);
}

#define DSR(dst, base, IMM)                                                 \
  asm volatile("ds_read_b128 %0, %1 offset:" IMM : "=v"(dst) : "v"(base))

#define GLB(dst, addr, IMM)                                                 \
  asm volatile("global_load_dwordx4 %0, %1, off offset:" IMM : "=v"(dst) : "v"(addr))

__device__ __forceinline__ void swizzle_mn(int MB, int NB, int* mb, int* nb) {
  int flat = blockIdx.y * NB + blockIdx.x;
  if ((MB & 7) == 0) {
    int xcd = flat & 7;
    int j = flat >> 3;
    int rpx = MB >> 3;
    *nb = j / rpx;
    int rowin = j - *nb * rpx;
    *mb = (rowin << 3) | xcd;
  } else {
    *mb = blockIdx.y; *nb = blockIdx.x;
  }
}

// Stage one 16KB A half-tile: 16 wave-loads of 8 rows x 64 cols. LDS dest LINEAR;
// bank-swizzle via permuted GLOBAL source chunk (rule #21): chunk c holds c^(row&7).
__device__ __forceinline__ void stage_seg(const u16* __restrict__ G, int ld, int k0,
                                          u16* L, int rb0, int rb1,
                                          int wid, int lane) {
#pragma unroll
  for (int i = 0; i < 2; ++i) {
    int j = wid * 2 + i;
    int rs = (j < 8) ? (rb0 + j * 8) : (rb1 + (j - 8) * 8);   // wave-uniform
    int grow = rs + (lane >> 3);
    int gcol = k0 + (((lane & 7) ^ (lane >> 3)) << 3);
    gll16(G + (size_t)grow * ld + gcol, L + rs * 64);
  }
}

#define MFMA_Q(MQ, NQ)                                                           \
  {                                                                              \
    _Pragma("unroll") for (int mt = 0; mt < 4; ++mt) {                           \
      _Pragma("unroll") for (int nt = 0; nt < 2; ++nt) {                         \
        acc[(MQ)*4 + mt][(NQ)*2 + nt] = __builtin_amdgcn_mfma_f32_16x16x32_bf16( \
            af[mt][0], bfr[NQ][nt][0], acc[(MQ)*4 + mt][(NQ)*2 + nt], 0, 0, 0);  \
        acc[(MQ)*4 + mt][(NQ)*2 + nt] = __builtin_amdgcn_mfma_f32_16x16x32_bf16( \
            af[mt][1], bfr[NQ][nt][1], acc[(MQ)*4 + mt][(NQ)*2 + nt], 0, 0, 0);  \
      }                                                                          \
    }                                                                            \
  }

#define WAIT_LGKM_FENCE()                                  \
  asm volatile("s_waitcnt lgkmcnt(0)" ::: "memory");       \
  __builtin_amdgcn_sched_barrier(0);

#define SB() __builtin_amdgcn_sched_barrier(0);

#define R_A_MQ0()                     \
  DSR(af[0][0], baseA0, "0");         \
  DSR(af[0][1], baseA1, "0");         \
  DSR(af[1][0], baseA0, "2048");      \
  DSR(af[1][1], baseA1, "2048");      \
  DSR(af[2][0], baseA0, "4096");      \
  DSR(af[2][1], baseA1, "4096");      \
  DSR(af[3][0], baseA0, "6144");      \
  DSR(af[3][1], baseA1, "6144");
#define R_A_MQ1()                     \
  DSR(af[0][0], baseA0, "8192");      \
  DSR(af[0][1], baseA1, "8192");      \
  DSR(af[1][0], baseA0, "10240");     \
  DSR(af[1][1], baseA1, "10240");     \
  DSR(af[2][0], baseA0, "12288");     \
  DSR(af[2][1], baseA1, "12288");     \
  DSR(af[3][0], baseA0, "14336");     \
  DSR(af[3][1], baseA1, "14336");
#define R_B_ALL()                        \
  GLB(bfr[0][0][0], bq0, "0");           \
  GLB(bfr[0][0][1], bq0, "1024");        \
  GLB(bfr[0][1][0], bq1, "0");           \
  GLB(bfr[0][1][1], bq1, "1024");        \
  GLB(bfr[1][0][0], bq2, "0");           \
  GLB(bfr[1][0][1], bq2, "1024");        \
  GLB(bfr[1][1][0], bq3, "0");           \
  GLB(bfr[1][1][1], bq3, "1024");

// C[M,N] = A[M,K](bf16, lda) * Bp(packed)^T (+bias). 512 threads, 8 waves 2Mx4N,
// per-wave 128x64 out. A: 4-ring LDS (4x32KB); stage h0(s+3)@ph1, h1(s+3)@ph2 —
// always writes ring slot (s-1)&3, disjoint from reads of s&3 under <=1-tile
// drift => ONE barrier per K-tile. B: packed fragments straight to regs, loaded
// at ph4 for tile s+1 (~1 tile of lead; L2-resident). Waits: vmcnt(2) once per
// tile (protects only A(s+3)-h0), lgkm(0) at ph1/ph3 for own 8-read batches.
template <int RELU, int OUTBF16, int HASBIAS>
__global__ __launch_bounds__(512, 2) void gemm256p(const u16* A, int lda,
                                                   const u16* Bp,
                                                   const float* __restrict__ bias,
                                                   void* Cp,
                                                   int M, int N, int K) {
  __shared__ __attribute__((aligned(16))) u16 As[4][256 * 64];   // 128 KiB
  int tid = threadIdx.x;
  int lane = tid & 63, wid = tid >> 6;
  int lm = lane & 15, quad = lane >> 4;
  int wr = wid >> 2, wc = wid & 3;
  int mb, nb;
  swizzle_mn(gridDim.y, gridDim.x, &mb, &nb);
  int m0 = mb * 256, n0 = nb * 256;
  const u16* Ag = A + (size_t)m0 * lda;
  int NT = K >> 6;

  int off0 = (quad ^ (lm & 7)) << 3;
  int off1 = ((4 + quad) ^ (lm & 7)) << 3;
  unsigned ldsA = (unsigned)(size_t)(l16c*)(&As[0][0]);
  unsigned rootA0 = ldsA + (unsigned)(((wr * 128 + lm) * 64 + off0) * 2);
  unsigned rootA1 = ldsA + (unsigned)(((wr * 128 + lm) * 64 + off1) * 2);

  // B fragment pointers (packed): g = nb*16 + wc*4 + j
  size_t bstep = (size_t)(N >> 4) * 1024;   // elems per K-tile
  const u16* bq0 = Bp + (size_t)(nb * 16 + wc * 4 + 0) * 1024 + lane * 8;
  const u16* bq1 = bq0 + 1024;
  const u16* bq2 = bq0 + 2048;
  const u16* bq3 = bq0 + 3072;

  fx4 acc[8][4] = {};
  s16x8 af[4][2];
  s16x8 bfr[2][2][2];

  // prologue: A(0..2) into ring 0..2; B(0) to regs. vmcnt(8) keeps B in flight.
  stage_seg(Ag, lda, 0, As[0], 0, 128, wid, lane);
  stage_seg(Ag, lda, 0, As[0], 64, 192, wid, lane);
  if (NT > 1) {
    stage_seg(Ag, lda, 64, As[1], 0, 128, wid, lane);
    stage_seg(Ag, lda, 64, As[1], 64, 192, wid, lane);
  }
  if (NT > 2) {
    stage_seg(Ag, lda, 128, As[2], 0, 128, wid, lane);
    stage_seg(Ag, lda, 128, As[2], 64, 192, wid, lane);
  }
  R_B_ALL();
  asm volatile("s_waitcnt vmcnt(8)" ::: "memory");
  __builtin_amdgcn_s_barrier();

  for (int s = 0; s < NT; ++s) {
    unsigned bsel = (unsigned)((s & 3) << 15);
    unsigned baseA0 = rootA0 + bsel, baseA1 = rootA1 + bsel;
    int k3 = (s + 3) << 6;
    u16* An3 = As[(s + 3) & 3];
    SB()
    // ---- ph1: read A-mq0; stage A(s+3) h0; vmcnt; MFMA (0,0)
    R_A_MQ0();
    if (s + 3 < NT) {
      stage_seg(Ag, lda, k3, An3, 0, 128, wid, lane);
      asm volatile("s_waitcnt vmcnt(2)" ::: "memory");
    } else {
      asm volatile("s_waitcnt vmcnt(0)" ::: "memory");
    }
    WAIT_LGKM_FENCE()
    __builtin_amdgcn_s_setprio(1);
    MFMA_Q(0, 0)
    __builtin_amdgcn_s_setprio(0);
    SB()
    // ---- ph2: stage A(s+3) h1; MFMA (0,1)  (no waits)
    if (s + 3 < NT) stage_seg(Ag, lda, k3, An3, 64, 192, wid, lane);
    __builtin_amdgcn_s_setprio(1);
    MFMA_Q(0, 1)
    __builtin_amdgcn_s_setprio(0);
    SB()
    // ---- ph3: read A-mq1; MFMA (1,1)
    R_A_MQ1();
    WAIT_LGKM_FENCE()
    __builtin_amdgcn_s_setprio(1);
    MFMA_Q(1, 1)
    __builtin_amdgcn_s_setprio(0);
    SB()
    // ---- ph4: MFMA (1,0); load B(s+1); tile barrier
    __builtin_amdgcn_s_setprio(1);
    MFMA_Q(1, 0)
    __builtin_amdgcn_s_setprio(0);
    SB()
    if (s + 1 < NT) {
      bq0 += bstep; bq1 += bstep; bq2 += bstep; bq3 += bstep;
      R_B_ALL();
    }
    __builtin_amdgcn_s_barrier();
  }

  // epilogue
  float* Cf = (float*)Cp;
  u16* Ch = (u16*)Cp;
#pragma unroll
  for (int ai = 0; ai < 8; ++ai) {
#pragma unroll
    for (int bi = 0; bi < 4; ++bi) {
      int col = n0 + wc * 64 + (bi >> 1) * 32 + (bi & 1) * 16 + lm;
      float bv = HASBIAS ? bias[col] : 0.f;
#pragma unroll
      for (int r = 0; r < 4; ++r) {
        int row = m0 + wr * 128 + (ai >> 2) * 64 + (ai & 3) * 16 + quad * 4 + r;
        float v = acc[ai][bi][r] + bv;
        if (RELU) v = v > 0.f ? v : 0.f;
        if (OUTBF16) Ch[(size_t)row * N + col] = f2bf(v);
        else         Cf[(size_t)row * N + col] = v;
      }
    }
  }
}

// ---------------- MFMA flash attention ----------------
#define PADK 72
#define PADV 136
#define PADP 40
#define PADO 72

__global__ __launch_bounds__(256, 2) void attn_mfma(u16* qkv) {
  __shared__ __attribute__((aligned(16))) u16 lds[38400];   // 76.8 KB
  u16* Klds  = lds;                    // 128 x PADK = 9216
  u16* Vtlds = lds + 9216;             // 64 x PADV  = 8704

  int bid = blockIdx.x;
  int h = bid & (Hh - 1);
  int c = (bid >> 4) & (NC - 1);
  int b = bid >> 8;
  int tid = threadIdx.x, lane = tid & 63, w = tid >> 6;
  int lm = lane & 15, quad = lane >> 4;
  u16* Pw = lds + 17920 + w * 5120;

  size_t rowbase = (size_t)b * Lseq;

  s16x8 qf[4][2];
#pragma unroll
  for (int nt = 0; nt < 4; ++nt)
#pragma unroll
    for (int ks = 0; ks < 2; ++ks) {
      int qtok = c * Wc + w * 64 + nt * 16 + lm;
      qf[nt][ks] = *(const s16x8*)(qkv + (rowbase + qtok) * 3072 + h * 64 + ks * 32 + quad * 8);
    }

  fx4 acc_o[4][4] = {};
  float lsum[4] = {0.f, 0.f, 0.f, 0.f};

  int nph = (c > 0) ? 4 : 2;
  int t0  = (c > 0) ? (c - 1) * Wc : 0;

  for (int ph = 0; ph < nph; ++ph) {
    int kt0 = t0 + ph * 128;
    __syncthreads();

#pragma unroll
    for (int it = 0; it < 4; ++it) {
      int s = tid + it * 256;
      int row = s >> 3, off = (s & 7) * 8;
      uint4 kv = *(const uint4*)(qkv + (rowbase + kt0 + row) * 3072 + 1024 + h * 64 + off);
      *(uint4*)(Klds + row * PADK + off) = kv;
    }
    {
      int d = lane;
      int kb = w * 32;
      u16 tmp[32];
#pragma unroll
      for (int i = 0; i < 32; ++i)
        tmp[i] = qkv[(rowbase + kt0 + kb + i) * 3072 + 2048 + h * 64 + d];
#pragma unroll
      for (int i = 0; i < 4; ++i)
        *(uint4*)(Vtlds + d * PADV + kb + i * 8) = *(const uint4*)(tmp + i * 8);
    }
    __syncthreads();

#pragma unroll
    for (int kt = 0; kt < 4; ++kt) {
      u16* Pb = Pw + (kt & 1) * 2560;
      fx4 sa[2][4] = {};
#pragma unroll
      for (int ks = 0; ks < 2; ++ks) {
        s16x8 kf0 = *(const s16x8*)(Klds + (kt * 32 + lm) * PADK + ks * 32 + quad * 8);
        s16x8 kf1 = *(const s16x8*)(Klds + (kt * 32 + 16 + lm) * PADK + ks * 32 + quad * 8);
#pragma unroll
        for (int nt = 0; nt < 4; ++nt) {
          sa[0][nt] = __builtin_amdgcn_mfma_f32_16x16x32_bf16(kf0, qf[nt][ks], sa[0][nt], 0, 0, 0);
          sa[1][nt] = __builtin_amdgcn_mfma_f32_16x16x32_bf16(kf1, qf[nt][ks], sa[1][nt], 0, 0, 0);
        }
      }
#pragma unroll
      for (int mt = 0; mt < 2; ++mt)
#pragma unroll
        for (int nt = 0; nt < 4; ++nt) {
          float e0 = __expf(sa[mt][nt][0] * 0.125f);
          float e1 = __expf(sa[mt][nt][1] * 0.125f);
          float e2 = __expf(sa[mt][nt][2] * 0.125f);
          float e3 = __expf(sa[mt][nt][3] * 0.125f);
          lsum[nt] += (e0 + e1) + (e2 + e3);
          uint2 pk; pk.x = pack2bf(e0, e1); pk.y = pack2bf(e2, e3);
          *(uint2*)(Pb + (nt * 16 + lm) * PADP + mt * 16 + quad * 4) = pk;
        }
#pragma unroll
      for (int mt = 0; mt < 4; ++mt) {
        s16x8 vf = *(const s16x8*)(Vtlds + (mt * 16 + lm) * PADV + kt * 32 + quad * 8);
#pragma unroll
        for (int nt = 0; nt < 4; ++nt) {
          s16x8 pf = *(const s16x8*)(Pb + (nt * 16 + lm) * PADP + quad * 8);
          acc_o[mt][nt] = __builtin_amdgcn_mfma_f32_16x16x32_bf16(vf, pf, acc_o[mt][nt], 0, 0, 0);
        }
      }
    }
  }

#pragma unroll
  for (int nt = 0; nt < 4; ++nt) {
    float v = lsum[nt];
    v += __shfl_xor(v, 16, 64);
    v += __shfl_xor(v, 32, 64);
    lsum[nt] = 1.f / v;
  }

  __syncthreads();
  u16* Obuf = lds;
#pragma unroll
  for (int mt = 0; mt < 4; ++mt)
#pragma unroll
    for (int nt = 0; nt < 4; ++nt) {
      float inv = lsum[nt];
      uint2 pk;
      pk.x = pack2bf(acc_o[mt][nt][0] * inv, acc_o[mt][nt][1] * inv);
      pk.y = pack2bf(acc_o[mt][nt][2] * inv, acc_o[mt][nt][3] * inv);
      int q = nt * 16 + lm;
      *(uint2*)(Obuf + (w * 64 + q) * PADO + mt * 16 + quad * 4) = pk;
    }
  __syncthreads();
#pragma unroll
  for (int it = 0; it < 8; ++it) {
    int s = tid + it * 256;
    int row = s >> 3, chunk = s & 7;
    uint4 v = *(const uint4*)(Obuf + row * PADO + chunk * 8);
    *(uint4*)(qkv + (rowbase + c * Wc + row) * 3072 + h * 64 + chunk * 8) = v;
  }
}

// ---------------- layernorm variants ----------------
__device__ __forceinline__ void ln_core(float sx, float sy, float sz, float sw,
                                        const float* gamma, const float* beta, int tid,
                                        float* red, float4* outv) {
  float part = sx + sy + sz + sw;
#pragma unroll
  for (int off = 32; off > 0; off >>= 1) part += __shfl_down(part, off, 64);
  if ((tid & 63) == 0) red[tid >> 6] = part;
  __syncthreads();
  float mean = (red[0] + red[1] + red[2] + red[3]) * (1.f / 1024.f);
  __syncthreads();

  float dx = sx - mean, dy = sy - mean, dz = sz - mean, dw = sw - mean;
  float sq = dx * dx + dy * dy + dz * dz + dw * dw;
#pragma unroll
  for (int off = 32; off > 0; off >>= 1) sq += __shfl_down(sq, off, 64);
  if ((tid & 63) == 0) red[tid >> 6] = sq;
  __syncthreads();
  float var = (red[0] + red[1] + red[2] + red[3]) * (1.f / 1024.f);
  float rs = rsqrtf(var + 1e-6f);

  float4 g = *(const float4*)(gamma + tid * 4);
  float4 be = *(const float4*)(beta + tid * 4);
  outv->x = g.x * dx * rs + be.x;
  outv->y = g.y * dy * rs + be.y;
  outv->z = g.z * dz * rs + be.z;
  outv->w = g.w * dw * rs + be.w;
}

__global__ __launch_bounds__(256) void ln1_kernel(const float* __restrict__ r,
                                                  const float* __restrict__ dl,
                                                  const float* __restrict__ gamma,
                                                  const float* __restrict__ beta,
                                                  u16* __restrict__ outh) {
  __shared__ float red[4];
  int row = blockIdx.x, tid = threadIdx.x;
  size_t base = (size_t)row * Dm;
  float4 rv = *(const float4*)(r + base + tid * 4);
  float4 dv = *(const float4*)(dl + base + tid * 4);
  float4 o;
  ln_core(rv.x + dv.x, rv.y + dv.y, rv.z + dv.z, rv.w + dv.w, gamma, beta, tid, red, &o);
  u16 u[4] = { f2bf(o.x), f2bf(o.y), f2bf(o.z), f2bf(o.w) };
  *(uint2*)(outh + base + tid * 4) = *(const uint2*)u;
}

// LN2: sum = bf16 x1 + f32 y2 + colbias (bf2); -> f32 out (in-place ok)
__global__ __launch_bounds__(256) void ln2_kernel(const u16* __restrict__ r,
                                                  const float* dl,
                                                  const float* __restrict__ colbias,
                                                  const float* __restrict__ gamma,
                                                  const float* __restrict__ beta,
                                                  float* outf) {
  __shared__ float red[4];
  int row = blockIdx.x, tid = threadIdx.x;
  size_t base = (size_t)row * Dm;
  uint2 ru = *(const uint2*)(r + base + tid * 4);
  const u16* pu = (const u16*)&ru;
  float4 dv = *(const float4*)(dl + base + tid * 4);
  float4 bb = *(const float4*)(colbias + tid * 4);
  float4 o;
  ln_core(bf2f(pu[0]) + dv.x + bb.x, bf2f(pu[1]) + dv.y + bb.y,
          bf2f(pu[2]) + dv.z + bb.z, bf2f(pu[3]) + dv.w + bb.w,
          gamma, beta, tid, red, &o);
  *(float4*)(outf + base + tid * 4) = o;
}

// ---------------- launch ----------------
extern "C" void kernel_launch(void* const* d_in, const int* in_sizes, int n_in,
                              void* d_out, int out_size, void* d_ws, size_t ws_size,
                              hipStream_t stream) {
  const float* x         = (const float*)d_in[0];
  const float* in_proj_w = (const float*)d_in[1];
  const float* in_proj_b = (const float*)d_in[2];
  const float* out_w     = (const float*)d_in[3];
  const float* out_b     = (const float*)d_in[4];
  const float* gamma1    = (const float*)d_in[5];
  const float* beta1     = (const float*)d_in[6];
  const float* w1        = (const float*)d_in[7];
  const float* bf1       = (const float*)d_in[8];
  const float* w2        = (const float*)d_in[9];
  const float* bf2       = (const float*)d_in[10];
  const float* gamma2    = (const float*)d_in[11];
  const float* beta2     = (const float*)d_in[12];
  float* out = (float*)d_out;

  char* ws = (char*)d_ws;
  size_t off = 0;
  auto alloc = [&](size_t bytes) -> char* {
    char* p = ws + off;
    off += (bytes + 255) & ~(size_t)255;
    return p;
  };
  u16* wqkvp = (u16*)alloc((size_t)3 * Dm * Dm * 2);
  u16* owp   = (u16*)alloc((size_t)Dm * Dm * 2);
  u16* w1p   = (u16*)alloc((size_t)FFd * Dm * 2);
  u16* w2p   = (u16*)alloc((size_t)Dm * FFd * 2);
  u16* big   = (u16*)alloc((size_t)NTOK * FFd * 2);
  u16* x1h   = (u16*)alloc((size_t)NTOK * Dm * 2);
  u16* qkvh = big;
  u16* hh   = big;
  u16* xh   = (u16*)d_out;
  float* attnf = out;
  float* y2f   = out;

  cvt_f32_bf16<<<(long)NTOK * Dm / 1024, 256, 0, stream>>>(x, xh, (long)NTOK * Dm);
  pack_f32_nk<<<(3 * Dm * Dm) / 2048, 256, 0, stream>>>(in_proj_w, wqkvp, 3 * Dm, Dm);
  pack_f32_nk<<<(Dm * Dm) / 2048, 256, 0, stream>>>(out_w, owp, Dm, Dm);
  transpose_pack_f32<<<dim3(FFd / 32, Dm / 64), 256, 0, stream>>>(w1, w1p, FFd, Dm);
  transpose_pack_f32<<<dim3(Dm / 32, FFd / 64), 256, 0, stream>>>(w2, w2p, Dm, FFd);

  // QKV projection: [16384,1024] x [3072,1024]^T -> bf16 [16384,3072]
  gemm256p<0, 1, 1><<<dim3(3 * Dm / 256, NTOK / 256), 512, 0, stream>>>(
      xh, Dm, wqkvp, in_proj_b, qkvh, NTOK, 3 * Dm, Dm);

  attn_mfma<<<Bsz * NC * Hh, 256, 0, stream>>>(qkvh);

  // out projection: attn-out (qkv cols 0..1023) x out_w^T -> f32
  gemm256p<0, 0, 1><<<dim3(Dm / 256, NTOK / 256), 512, 0, stream>>>(
      qkvh, 3 * Dm, owp, out_b, attnf, NTOK, Dm, Dm);

  ln1_kernel<<<NTOK, 256, 0, stream>>>(x, attnf, gamma1, beta1, x1h);

  // FFN1 + ReLU -> bf16 [16384,4096]
  gemm256p<1, 1, 1><<<dim3(FFd / 256, NTOK / 256), 512, 0, stream>>>(
      x1h, Dm, w1p, bf1, hh, NTOK, FFd, Dm);

  // FFN2 -> f32 (bias bf2 folded into LN2)
  gemm256p<0, 0, 0><<<dim3(Dm / 256, NTOK / 256), 512, 0, stream>>>(
      hh, FFd, w2p, (const float*)nullptr, y2f, NTOK, Dm, FFd);

  ln2_kernel<<<NTOK, 256, 0, stream>>>(x1h, y2f, bf2, gamma2, beta2, out);
}

// Round 6
// 661.547 us; speedup vs baseline: 1.3219x; 1.0266x over previous
//
#include <hip/hip_runtime.h>
#include <stdint.h>

#define Bsz 4
#define Lseq 4096
#define Dm 1024
#define Hh 16
#define Wc 256
#define FFd 4096
#define NC 16
#define NTOK (Bsz * Lseq)   // 16384

typedef unsigned short u16;

__device__ __forceinline__ float bf2f(u16 u) {
  union { unsigned int i; float f; } v; v.i = ((unsigned int)u) << 16; return v.f;
}
__device__ __forceinline__ u16 f2bf(float f) {
  union { float f; unsigned int i; } v; v.f = f;
  unsigned int r = v.i + 0x7fffu + ((v.i >> 16) & 1u);
  return (u16)(r >> 16);
}
__device__ __forceinline__ unsigned int pack2bf(float a, float b) {
  union { float f; unsigned int u; } x, y; x.f = a; y.f = b;
  return ((x.u + 0x8000u) >> 16) | ((y.u + 0x8000u) & 0xffff0000u);
}

// ---------------- utility kernels ----------------
__global__ void cvt_f32_bf16(const float* __restrict__ in, u16* __restrict__ out, long n) {
  long i = ((long)blockIdx.x * blockDim.x + threadIdx.x) * 4;
  if (i >= n) return;
  float4 v = *(const float4*)(in + i);
  u16 o[4] = { f2bf(v.x), f2bf(v.y), f2bf(v.z), f2bf(v.w) };
  *(uint2*)(out + i) = *(const uint2*)o;
}

// ---- weight packing into MFMA-fragment order ----
// Packed layout: chunk c = ((t*(N/16)+g)*2+ks) of 512 u16; element c*512 + lane*8,
// lane = quad*16+lm, holding B[n = g*16+lm][k = t*64 + ks*32 + quad*8 .. +8].

// W [N,K] f32 row-major -> packed bf16
__global__ void pack_f32_nk(const float* __restrict__ W, u16* __restrict__ P, int N, int K) {
  long idx = (long)blockIdx.x * 256 + threadIdx.x;     // one 8-elem group per thread
  int lane = (int)(idx & 63);
  long c = idx >> 6;
  int ks = (int)(c & 1);
  long c2 = c >> 1;
  int g = (int)(c2 % (N >> 4));
  int t = (int)(c2 / (N >> 4));
  int n = g * 16 + (lane & 15);
  int k = t * 64 + ks * 32 + (lane >> 4) * 8;
  const float* src = W + (size_t)n * K + k;
  u16 o[8];
#pragma unroll
  for (int e = 0; e < 8; ++e) o[e] = f2bf(src[e]);
  *(uint4*)(P + idx * 8) = *(const uint4*)o;
}

// W [K,N] f32 row-major (so B = W^T, [N,K]) -> packed bf16. grid (N/32, K/64), 256 thr.
__global__ void transpose_pack_f32(const float* __restrict__ W, u16* __restrict__ P,
                                   int N, int K) {
  __shared__ float t64[64][33];
  int tid = threadIdx.x;
  int n0 = blockIdx.x * 32, k0 = blockIdx.y * 64;
  int tx = tid & 31, ty = tid >> 5;   // 32 x 8
#pragma unroll
  for (int p = 0; p < 8; ++p)
    t64[ty + 8 * p][tx] = W[(size_t)(k0 + ty + 8 * p) * N + n0 + tx];
  __syncthreads();
  int nl = tid & 31, kq = tid >> 5;       // group: n-local 0..31, k-octet 0..7
  int ks = kq >> 2, quad = kq & 3;
  int g = (n0 >> 4) + (nl >> 4);
  int lmv = nl & 15;
  int t = k0 >> 6;
  u16 o[8];
#pragma unroll
  for (int e = 0; e < 8; ++e) o[e] = f2bf(t64[kq * 8 + e][nl]);
  size_t c = ((size_t)t * (N >> 4) + g) * 2 + ks;
  *(uint4*)(P + c * 512 + (quad * 16 + lmv) * 8) = *(const uint4*)o;
}

// ---------------- GEMM: 256x256 tile, BK=64, A-ring LDS + B-from-global,
// ---------------- anti-phase wave groups ----------------
typedef __attribute__((ext_vector_type(8))) short s16x8;
typedef __attribute__((ext_vector_type(4))) float fx4;
typedef __attribute__((address_space(1))) unsigned int as1u;
typedef __attribute__((address_space(3))) unsigned int as3u;
typedef __attribute__((address_space(3))) const u16 l16c;

__device__ __forceinline__ void gll16(const void* g, void* l) {
  __builtin_amdgcn_global_load_lds((as1u*)g, (as3u*)l, 16, 0, 0);
}

#define DSR(dst, base, IMM)                                                 \
  asm volatile("ds_read_b128 %0, %1 offset:" IMM : "=v"(dst) : "v"(base))

#define GLB(dst, addr, IMM)                                                 \
  asm volatile("global_load_dwordx4 %0, %1, off offset:" IMM : "=v"(dst) : "v"(addr))

__device__ __forceinline__ void swizzle_mn(int MB, int NB, int* mb, int* nb) {
  int flat = blockIdx.y * NB + blockIdx.x;
  if ((MB & 7) == 0) {
    int xcd = flat & 7;
    int j = flat >> 3;
    int rpx = MB >> 3;
    *nb = j / rpx;
    int rowin = j - *nb * rpx;
    *mb = (rowin << 3) | xcd;
  } else {
    *mb = blockIdx.y; *nb = blockIdx.x;
  }
}

#define MFMA_Q(MQ, NQ)                                                           \
  {                                                                              \
    _Pragma("unroll") for (int mt = 0; mt < 4; ++mt) {                           \
      _Pragma("unroll") for (int nt = 0; nt < 2; ++nt) {                         \
        acc[(MQ)*4 + mt][(NQ)*2 + nt] = __builtin_amdgcn_mfma_f32_16x16x32_bf16( \
            af[mt][0], bfr[NQ][nt][0], acc[(MQ)*4 + mt][(NQ)*2 + nt], 0, 0, 0);  \
        acc[(MQ)*4 + mt][(NQ)*2 + nt] = __builtin_amdgcn_mfma_f32_16x16x32_bf16( \
            af[mt][1], bfr[NQ][nt][1], acc[(MQ)*4 + mt][(NQ)*2 + nt], 0, 0, 0);  \
      }                                                                          \
    }                                                                            \
  }

#define WAIT_LGKM_FENCE()                                  \
  asm volatile("s_waitcnt lgkmcnt(0)" ::: "memory");       \
  __builtin_amdgcn_sched_barrier(0);

#define SB() __builtin_amdgcn_sched_barrier(0);

#define R_A_MQ0()                     \
  DSR(af[0][0], baseA0, "0");         \
  DSR(af[0][1], baseA1, "0");         \
  DSR(af[1][0], baseA0, "2048");      \
  DSR(af[1][1], baseA1, "2048");      \
  DSR(af[2][0], baseA0, "4096");      \
  DSR(af[2][1], baseA1, "4096");      \
  DSR(af[3][0], baseA0, "6144");      \
  DSR(af[3][1], baseA1, "6144");
#define R_A_MQ1()                     \
  DSR(af[0][0], baseA0, "8192");      \
  DSR(af[0][1], baseA1, "8192");      \
  DSR(af[1][0], baseA0, "10240");     \
  DSR(af[1][1], baseA1, "10240");     \
  DSR(af[2][0], baseA0, "12288");     \
  DSR(af[2][1], baseA1, "12288");     \
  DSR(af[3][0], baseA0, "14336");     \
  DSR(af[3][1], baseA1, "14336");
#define R_B_ALL()                        \
  GLB(bfr[0][0][0], bq0, "0");           \
  GLB(bfr[0][0][1], bq0, "1024");        \
  GLB(bfr[0][1][0], bq1, "0");           \
  GLB(bfr[0][1][1], bq1, "1024");        \
  GLB(bfr[1][0][0], bq2, "0");           \
  GLB(bfr[1][0][1], bq2, "1024");        \
  GLB(bfr[1][1][0], bq3, "0");           \
  GLB(bfr[1][1][1], bq3, "1024");

// stage half-tiles via persistent per-lane pointers (bumped 64 elems/tile)
#define STAGE_H0(slot)                                         \
  gll16(pA00, AsB + ((unsigned)(slot) << 15) + d00);           \
  gll16(pA01, AsB + ((unsigned)(slot) << 15) + d01);
#define STAGE_H1(slot)                                         \
  gll16(pA10, AsB + ((unsigned)(slot) << 15) + d10);           \
  gll16(pA11, AsB + ((unsigned)(slot) << 15) + d11);
#define BUMP_A() { pA00 += 64; pA01 += 64; pA10 += 64; pA11 += 64; }

// One K-tile body, quadrant order (Xq first-A-half, Yq second), literal indices.
// ph1: read A-Xq; stage h0(s+3); vmcnt; lgkm; MFMA(Xq,N1)
// ph2: stage h1(s+3); MFMA(Xq,N2)
// ph3: read A-Yq; lgkm; MFMA(Yq,N2)
// ph4: MFMA(Yq,N1); B(s+1) loads; barrier
#define TILE_BODY(RAX, RAY, XQ, YQ, N1, N2)                         \
  {                                                                 \
    SB()                                                            \
    RAX();                                                          \
    if (s + 3 < NT) {                                               \
      int slot = (s + 3) & 3;                                       \
      STAGE_H0(slot);                                               \
      asm volatile("s_waitcnt vmcnt(2)" ::: "memory");              \
    } else {                                                        \
      asm volatile("s_waitcnt vmcnt(0)" ::: "memory");              \
    }                                                               \
    WAIT_LGKM_FENCE()                                               \
    __builtin_amdgcn_s_setprio(1);                                  \
    MFMA_Q(XQ, N1)                                                  \
    __builtin_amdgcn_s_setprio(0);                                  \
    SB()                                                            \
    if (s + 3 < NT) { int slot = (s + 3) & 3; STAGE_H1(slot); }     \
    BUMP_A()                                                        \
    __builtin_amdgcn_s_setprio(1);                                  \
    MFMA_Q(XQ, N2)                                                  \
    __builtin_amdgcn_s_setprio(0);                                  \
    SB()                                                            \
    RAY();                                                          \
    WAIT_LGKM_FENCE()                                               \
    __builtin_amdgcn_s_setprio(1);                                  \
    MFMA_Q(YQ, N2)                                                  \
    __builtin_amdgcn_s_setprio(0);                                  \
    SB()                                                            \
    __builtin_amdgcn_s_setprio(1);                                  \
    MFMA_Q(YQ, N1)                                                  \
    __builtin_amdgcn_s_setprio(0);                                  \
    SB()                                                            \
    if (s + 1 < NT) {                                               \
      bq0 += bstep; bq1 += bstep; bq2 += bstep; bq3 += bstep;       \
      R_B_ALL();                                                    \
    }                                                               \
    __builtin_amdgcn_s_barrier();                                   \
  }

// C[M,N] = A[M,K](bf16,lda) * Bp(packed)^T (+bias). 512 thr, 8 waves 2Mx4N.
// A: 4-ring LDS (4x32KB). B: packed frags straight to regs, 1 tile of lead.
// ANTI-PHASE GROUPS: waves 0-3 (wr=0) run quadrants (0,*),(1,*); waves 4-7
// (wr=1) run (1,*),(0,*). SIMD k hosts waves {k, k+4} = one per group, so one
// wave's ds_read/lgkm window overlaps the other's MFMA cluster.
template <int RELU, int OUTBF16, int HASBIAS>
__global__ __launch_bounds__(512, 2) void gemm256r(const u16* A, int lda,
                                                   const u16* Bp,
                                                   const float* __restrict__ bias,
                                                   void* Cp,
                                                   int M, int N, int K) {
  __shared__ __attribute__((aligned(16))) u16 As[4][256 * 64];   // 128 KiB
  int tid = threadIdx.x;
  int lane = tid & 63, wid = tid >> 6;
  int lm = lane & 15, quad = lane >> 4;
  int wr = wid >> 2, wc = wid & 3;
  int mb, nb;
  swizzle_mn(gridDim.y, gridDim.x, &mb, &nb);
  int m0 = mb * 256, n0 = nb * 256;
  const u16* Ag = A + (size_t)m0 * lda;
  int NT = K >> 6;

  int off0 = (quad ^ (lm & 7)) << 3;
  int off1 = ((4 + quad) ^ (lm & 7)) << 3;
  unsigned ldsA = (unsigned)(size_t)(l16c*)(&As[0][0]);
  unsigned baseA0 = ldsA + (unsigned)(((wr * 128 + lm) * 64 + off0) * 2);
  unsigned baseA1 = ldsA + (unsigned)(((wr * 128 + lm) * 64 + off1) * 2);
  char* AsB = (char*)&As[0][0];

  // staging state: 4 persistent per-lane global pointers + wave-uniform LDS offs
  int j0 = wid * 2, j1 = wid * 2 + 1;
  int rs00 = (j0 < 8) ? j0 * 8 : 128 + (j0 - 8) * 8;        // h0 rows
  int rs01 = (j1 < 8) ? j1 * 8 : 128 + (j1 - 8) * 8;
  int rs10 = rs00 + 64, rs11 = rs01 + 64;                    // h1 rows
  int lrow = lane >> 3;
  int gsw = ((lane & 7) ^ lrow) << 3;
  const u16* pA00 = Ag + (size_t)(rs00 + lrow) * lda + gsw;
  const u16* pA01 = Ag + (size_t)(rs01 + lrow) * lda + gsw;
  const u16* pA10 = Ag + (size_t)(rs10 + lrow) * lda + gsw;
  const u16* pA11 = Ag + (size_t)(rs11 + lrow) * lda + gsw;
  unsigned d00 = (unsigned)rs00 * 128, d01 = (unsigned)rs01 * 128;
  unsigned d10 = (unsigned)rs10 * 128, d11 = (unsigned)rs11 * 128;

  // B fragment pointers (packed): g = nb*16 + wc*4 + j
  size_t bstep = (size_t)(N >> 4) * 1024;   // elems per K-tile
  const u16* bq0 = Bp + (size_t)(nb * 16 + wc * 4 + 0) * 1024 + lane * 8;
  const u16* bq1 = bq0 + 1024;
  const u16* bq2 = bq0 + 2048;
  const u16* bq3 = bq0 + 3072;

  fx4 acc[8][4] = {};
  s16x8 af[4][2];
  s16x8 bfr[2][2][2];

  // prologue: A(0..2) into ring 0..2; B(0) to regs. vmcnt(8) keeps B in flight.
  STAGE_H0(0); STAGE_H1(0); BUMP_A();
  if (NT > 1) { STAGE_H0(1); STAGE_H1(1); }
  BUMP_A();
  if (NT > 2) { STAGE_H0(2); STAGE_H1(2); }
  BUMP_A();
  R_B_ALL();
  asm volatile("s_waitcnt vmcnt(8)" ::: "memory");
  __builtin_amdgcn_s_barrier();

  if (wr == 0) {
    for (int s = 0; s < NT; ++s) {
      unsigned bsel = (unsigned)((s & 3) << 15);
      unsigned bA0 = baseA0 + bsel, bA1 = baseA1 + bsel;
      {
        unsigned baseA0 = bA0, baseA1 = bA1;   // shadow for macros
        TILE_BODY(R_A_MQ0, R_A_MQ1, 0, 1, 0, 1)
      }
    }
  } else {
    for (int s = 0; s < NT; ++s) {
      unsigned bsel = (unsigned)((s & 3) << 15);
      unsigned bA0 = baseA0 + bsel, bA1 = baseA1 + bsel;
      {
        unsigned baseA0 = bA0, baseA1 = bA1;
        TILE_BODY(R_A_MQ1, R_A_MQ0, 1, 0, 0, 1)
      }
    }
  }

  // epilogue
  float* Cf = (float*)Cp;
  u16* Ch = (u16*)Cp;
#pragma unroll
  for (int ai = 0; ai < 8; ++ai) {
#pragma unroll
    for (int bi = 0; bi < 4; ++bi) {
      int col = n0 + wc * 64 + (bi >> 1) * 32 + (bi & 1) * 16 + lm;
      float bv = HASBIAS ? bias[col] : 0.f;
#pragma unroll
      for (int r = 0; r < 4; ++r) {
        int row = m0 + wr * 128 + (ai >> 2) * 64 + (ai & 3) * 16 + quad * 4 + r;
        float v = acc[ai][bi][r] + bv;
        if (RELU) v = v > 0.f ? v : 0.f;
        if (OUTBF16) Ch[(size_t)row * N + col] = f2bf(v);
        else         Cf[(size_t)row * N + col] = v;
      }
    }
  }
}

// ---------------- MFMA flash attention ----------------
#define PADK 72
#define PADV 136
#define PADP 40
#define PADO 72

__global__ __launch_bounds__(256, 2) void attn_mfma(u16* qkv) {
  __shared__ __attribute__((aligned(16))) u16 lds[38400];   // 76.8 KB
  u16* Klds  = lds;                    // 128 x PADK = 9216
  u16* Vtlds = lds + 9216;             // 64 x PADV  = 8704

  int bid = blockIdx.x;
  int h = bid & (Hh - 1);
  int c = (bid >> 4) & (NC - 1);
  int b = bid >> 8;
  int tid = threadIdx.x, lane = tid & 63, w = tid >> 6;
  int lm = lane & 15, quad = lane >> 4;
  u16* Pw = lds + 17920 + w * 5120;

  size_t rowbase = (size_t)b * Lseq;

  s16x8 qf[4][2];
#pragma unroll
  for (int nt = 0; nt < 4; ++nt)
#pragma unroll
    for (int ks = 0; ks < 2; ++ks) {
      int qtok = c * Wc + w * 64 + nt * 16 + lm;
      qf[nt][ks] = *(const s16x8*)(qkv + (rowbase + qtok) * 3072 + h * 64 + ks * 32 + quad * 8);
    }

  fx4 acc_o[4][4] = {};
  float lsum[4] = {0.f, 0.f, 0.f, 0.f};

  int nph = (c > 0) ? 4 : 2;
  int t0  = (c > 0) ? (c - 1) * Wc : 0;

  for (int ph = 0; ph < nph; ++ph) {
    int kt0 = t0 + ph * 128;
    __syncthreads();

#pragma unroll
    for (int it = 0; it < 4; ++it) {
      int s = tid + it * 256;
      int row = s >> 3, off = (s & 7) * 8;
      uint4 kv = *(const uint4*)(qkv + (rowbase + kt0 + row) * 3072 + 1024 + h * 64 + off);
      *(uint4*)(Klds + row * PADK + off) = kv;
    }
    {
      int d = lane;
      int kb = w * 32;
      u16 tmp[32];
#pragma unroll
      for (int i = 0; i < 32; ++i)
        tmp[i] = qkv[(rowbase + kt0 + kb + i) * 3072 + 2048 + h * 64 + d];
#pragma unroll
      for (int i = 0; i < 4; ++i)
        *(uint4*)(Vtlds + d * PADV + kb + i * 8) = *(const uint4*)(tmp + i * 8);
    }
    __syncthreads();

#pragma unroll
    for (int kt = 0; kt < 4; ++kt) {
      u16* Pb = Pw + (kt & 1) * 2560;
      fx4 sa[2][4] = {};
#pragma unroll
      for (int ks = 0; ks < 2; ++ks) {
        s16x8 kf0 = *(const s16x8*)(Klds + (kt * 32 + lm) * PADK + ks * 32 + quad * 8);
        s16x8 kf1 = *(const s16x8*)(Klds + (kt * 32 + 16 + lm) * PADK + ks * 32 + quad * 8);
#pragma unroll
        for (int nt = 0; nt < 4; ++nt) {
          sa[0][nt] = __builtin_amdgcn_mfma_f32_16x16x32_bf16(kf0, qf[nt][ks], sa[0][nt], 0, 0, 0);
          sa[1][nt] = __builtin_amdgcn_mfma_f32_16x16x32_bf16(kf1, qf[nt][ks], sa[1][nt], 0, 0, 0);
        }
      }
#pragma unroll
      for (int mt = 0; mt < 2; ++mt)
#pragma unroll
        for (int nt = 0; nt < 4; ++nt) {
          float e0 = __expf(sa[mt][nt][0] * 0.125f);
          float e1 = __expf(sa[mt][nt][1] * 0.125f);
          float e2 = __expf(sa[mt][nt][2] * 0.125f);
          float e3 = __expf(sa[mt][nt][3] * 0.125f);
          lsum[nt] += (e0 + e1) + (e2 + e3);
          uint2 pk; pk.x = pack2bf(e0, e1); pk.y = pack2bf(e2, e3);
          *(uint2*)(Pb + (nt * 16 + lm) * PADP + mt * 16 + quad * 4) = pk;
        }
#pragma unroll
      for (int mt = 0; mt < 4; ++mt) {
        s16x8 vf = *(const s16x8*)(Vtlds + (mt * 16 + lm) * PADV + kt * 32 + quad * 8);
#pragma unroll
        for (int nt = 0; nt < 4; ++nt) {
          s16x8 pf = *(const s16x8*)(Pb + (nt * 16 + lm) * PADP + quad * 8);
          acc_o[mt][nt] = __builtin_amdgcn_mfma_f32_16x16x32_bf16(vf, pf, acc_o[mt][nt], 0, 0, 0);
        }
      }
    }
  }

#pragma unroll
  for (int nt = 0; nt < 4; ++nt) {
    float v = lsum[nt];
    v += __shfl_xor(v, 16, 64);
    v += __shfl_xor(v, 32, 64);
    lsum[nt] = 1.f / v;
  }

  __syncthreads();
  u16* Obuf = lds;
#pragma unroll
  for (int mt = 0; mt < 4; ++mt)
#pragma unroll
    for (int nt = 0; nt < 4; ++nt) {
      float inv = lsum[nt];
      uint2 pk;
      pk.x = pack2bf(acc_o[mt][nt][0] * inv, acc_o[mt][nt][1] * inv);
      pk.y = pack2bf(acc_o[mt][nt][2] * inv, acc_o[mt][nt][3] * inv);
      int q = nt * 16 + lm;
      *(uint2*)(Obuf + (w * 64 + q) * PADO + mt * 16 + quad * 4) = pk;
    }
  __syncthreads();
#pragma unroll
  for (int it = 0; it < 8; ++it) {
    int s = tid + it * 256;
    int row = s >> 3, chunk = s & 7;
    uint4 v = *(const uint4*)(Obuf + row * PADO + chunk * 8);
    *(uint4*)(qkv + (rowbase + c * Wc + row) * 3072 + h * 64 + chunk * 8) = v;
  }
}

// ---------------- layernorm variants ----------------
__device__ __forceinline__ void ln_core(float sx, float sy, float sz, float sw,
                                        const float* gamma, const float* beta, int tid,
                                        float* red, float4* outv) {
  float part = sx + sy + sz + sw;
#pragma unroll
  for (int off = 32; off > 0; off >>= 1) part += __shfl_down(part, off, 64);
  if ((tid & 63) == 0) red[tid >> 6] = part;
  __syncthreads();
  float mean = (red[0] + red[1] + red[2] + red[3]) * (1.f / 1024.f);
  __syncthreads();

  float dx = sx - mean, dy = sy - mean, dz = sz - mean, dw = sw - mean;
  float sq = dx * dx + dy * dy + dz * dz + dw * dw;
#pragma unroll
  for (int off = 32; off > 0; off >>= 1) sq += __shfl_down(sq, off, 64);
  if ((tid & 63) == 0) red[tid >> 6] = sq;
  __syncthreads();
  float var = (red[0] + red[1] + red[2] + red[3]) * (1.f / 1024.f);
  float rs = rsqrtf(var + 1e-6f);

  float4 g = *(const float4*)(gamma + tid * 4);
  float4 be = *(const float4*)(beta + tid * 4);
  outv->x = g.x * dx * rs + be.x;
  outv->y = g.y * dy * rs + be.y;
  outv->z = g.z * dz * rs + be.z;
  outv->w = g.w * dw * rs + be.w;
}

__global__ __launch_bounds__(256) void ln1_kernel(const float* __restrict__ r,
                                                  const float* __restrict__ dl,
                                                  const float* __restrict__ gamma,
                                                  const float* __restrict__ beta,
                                                  u16* __restrict__ outh) {
  __shared__ float red[4];
  int row = blockIdx.x, tid = threadIdx.x;
  size_t base = (size_t)row * Dm;
  float4 rv = *(const float4*)(r + base + tid * 4);
  float4 dv = *(const float4*)(dl + base + tid * 4);
  float4 o;
  ln_core(rv.x + dv.x, rv.y + dv.y, rv.z + dv.z, rv.w + dv.w, gamma, beta, tid, red, &o);
  u16 u[4] = { f2bf(o.x), f2bf(o.y), f2bf(o.z), f2bf(o.w) };
  *(uint2*)(outh + base + tid * 4) = *(const uint2*)u;
}

// LN2: sum = bf16 x1 + f32 y2 + colbias (bf2); -> f32 out (in-place ok)
__global__ __launch_bounds__(256) void ln2_kernel(const u16* __restrict__ r,
                                                  const float* dl,
                                                  const float* __restrict__ colbias,
                                                  const float* __restrict__ gamma,
                                                  const float* __restrict__ beta,
                                                  float* outf) {
  __shared__ float red[4];
  int row = blockIdx.x, tid = threadIdx.x;
  size_t base = (size_t)row * Dm;
  uint2 ru = *(const uint2*)(r + base + tid * 4);
  const u16* pu = (const u16*)&ru;
  float4 dv = *(const float4*)(dl + base + tid * 4);
  float4 bb = *(const float4*)(colbias + tid * 4);
  float4 o;
  ln_core(bf2f(pu[0]) + dv.x + bb.x, bf2f(pu[1]) + dv.y + bb.y,
          bf2f(pu[2]) + dv.z + bb.z, bf2f(pu[3]) + dv.w + bb.w,
          gamma, beta, tid, red, &o);
  *(float4*)(outf + base + tid * 4) = o;
}

// ---------------- launch ----------------
extern "C" void kernel_launch(void* const* d_in, const int* in_sizes, int n_in,
                              void* d_out, int out_size, void* d_ws, size_t ws_size,
                              hipStream_t stream) {
  const float* x         = (const float*)d_in[0];
  const float* in_proj_w = (const float*)d_in[1];
  const float* in_proj_b = (const float*)d_in[2];
  const float* out_w     = (const float*)d_in[3];
  const float* out_b     = (const float*)d_in[4];
  const float* gamma1    = (const float*)d_in[5];
  const float* beta1     = (const float*)d_in[6];
  const float* w1        = (const float*)d_in[7];
  const float* bf1       = (const float*)d_in[8];
  const float* w2        = (const float*)d_in[9];
  const float* bf2       = (const float*)d_in[10];
  const float* gamma2    = (const float*)d_in[11];
  const float* beta2     = (const float*)d_in[12];
  float* out = (float*)d_out;

  char* ws = (char*)d_ws;
  size_t off = 0;
  auto alloc = [&](size_t bytes) -> char* {
    char* p = ws + off;
    off += (bytes + 255) & ~(size_t)255;
    return p;
  };
  u16* wqkvp = (u16*)alloc((size_t)3 * Dm * Dm * 2);
  u16* owp   = (u16*)alloc((size_t)Dm * Dm * 2);
  u16* w1p   = (u16*)alloc((size_t)FFd * Dm * 2);
  u16* w2p   = (u16*)alloc((size_t)Dm * FFd * 2);
  u16* big   = (u16*)alloc((size_t)NTOK * FFd * 2);
  u16* x1h   = (u16*)alloc((size_t)NTOK * Dm * 2);
  u16* qkvh = big;
  u16* hh   = big;
  u16* xh   = (u16*)d_out;
  float* attnf = out;
  float* y2f   = out;

  cvt_f32_bf16<<<(long)NTOK * Dm / 1024, 256, 0, stream>>>(x, xh, (long)NTOK * Dm);
  pack_f32_nk<<<(3 * Dm * Dm) / 2048, 256, 0, stream>>>(in_proj_w, wqkvp, 3 * Dm, Dm);
  pack_f32_nk<<<(Dm * Dm) / 2048, 256, 0, stream>>>(out_w, owp, Dm, Dm);
  transpose_pack_f32<<<dim3(FFd / 32, Dm / 64), 256, 0, stream>>>(w1, w1p, FFd, Dm);
  transpose_pack_f32<<<dim3(Dm / 32, FFd / 64), 256, 0, stream>>>(w2, w2p, Dm, FFd);

  // QKV projection: [16384,1024] x [3072,1024]^T -> bf16 [16384,3072]
  gemm256r<0, 1, 1><<<dim3(3 * Dm / 256, NTOK / 256), 512, 0, stream>>>(
      xh, Dm, wqkvp, in_proj_b, qkvh, NTOK, 3 * Dm, Dm);

  attn_mfma<<<Bsz * NC * Hh, 256, 0, stream>>>(qkvh);

  // out projection: attn-out (qkv cols 0..1023) x out_w^T -> f32
  gemm256r<0, 0, 1><<<dim3(Dm / 256, NTOK / 256), 512, 0, stream>>>(
      qkvh, 3 * Dm, owp, out_b, attnf, NTOK, Dm, Dm);

  ln1_kernel<<<NTOK, 256, 0, stream>>>(x, attnf, gamma1, beta1, x1h);

  // FFN1 + ReLU -> bf16 [16384,4096]
  gemm256r<1, 1, 1><<<dim3(FFd / 256, NTOK / 256), 512, 0, stream>>>(
      x1h, Dm, w1p, bf1, hh, NTOK, FFd, Dm);

  // FFN2 -> f32 (bias bf2 folded into LN2)
  gemm256r<0, 0, 0><<<dim3(Dm / 256, NTOK / 256), 512, 0, stream>>>(
      hh, FFd, w2p, (const float*)nullptr, y2f, NTOK, Dm, FFd);

  ln2_kernel<<<NTOK, 256, 0, stream>>>(x1h, y2f, bf2, gamma2, beta2, out);
}